// Round 6
// baseline (4396.774 us; speedup 1.0000x reference)
//
#include <hip/hip_runtime.h>
#include <stdint.h>

typedef unsigned short ushort_t;
typedef float f32x4 __attribute__((ext_vector_type(4)));
typedef short short8 __attribute__((ext_vector_type(8)));

#define B_ 32
#define T_ 512
#define I_ 512
#define H_ 512
#define G_ 2048   // 4*H

// ---------- helpers ----------
__device__ __forceinline__ ushort_t f2bf(float f) {
    uint32_t u = __float_as_uint(f);
    u += 0x7FFFu + ((u >> 16) & 1u);   // RNE
    return (ushort_t)(u >> 16);
}
__device__ __forceinline__ float bf2f(ushort_t s) {
    return __uint_as_float(((uint32_t)s) << 16);
}
__device__ __forceinline__ float sigm(float x) { return 1.0f / (1.0f + __expf(-x)); }
__device__ __forceinline__ float tanhx(float x) {
    float e = __expf(-2.0f * fabsf(x));
    float t = (1.0f - e) / (1.0f + e);
    return x >= 0.0f ? t : -t;
}

// ---------- cast fp32 -> bf16 (vectorized) ----------
__global__ __launch_bounds__(256) void kcast(const float* __restrict__ in,
                                             ushort_t* __restrict__ out, int n4) {
    int i = blockIdx.x * 256 + threadIdx.x;
    if (i < n4) {
        float4 v = ((const float4*)in)[i];
        ushort4 o;
        o.x = f2bf(v.x); o.y = f2bf(v.y); o.z = f2bf(v.z); o.w = f2bf(v.w);
        ((ushort4*)out)[i] = o;
    }
}

// ---------- bias fold: bias = bx + bh ----------
__global__ __launch_bounds__(256) void kbias(const float* __restrict__ bx,
                                             const float* __restrict__ bh,
                                             float* __restrict__ bias) {
    int i = blockIdx.x * 256 + threadIdx.x;
    if (i < G_) bias[i] = bx[i] + bh[i];
}

// ---------- GEMM: gx[m][n'] = sum_k xb[m][k]*wxb[n][k] + bias[n], bf16 out ----------
// Column layout swizzled for krec: logical n = gate*512 + jj*16 + d  ->  n' = jj*64 + gate*16 + d
// so each recurrence block's per-(b,t) slice is 64 contiguous values.
__global__ __launch_bounds__(256, 2) void kgemm(const ushort_t* __restrict__ A,
                                                const ushort_t* __restrict__ Bm,
                                                const float* __restrict__ bias,
                                                ushort_t* __restrict__ C) {
    __shared__ __align__(16) ushort_t LA[4096];   // [128 rows][32 k] swizzled
    __shared__ __align__(16) ushort_t LB[4096];
    const int tid = threadIdx.x;
    const int lane = tid & 63, w = tid >> 6;
    const int quad = lane >> 4, l16 = lane & 15;
    const int bn = blockIdx.x, bm = blockIdx.y;
    const int wr = w >> 1, wc = w & 1;

    f32x4 acc[4][4] = {};

    for (int kt = 0; kt < 16; ++kt) {
#pragma unroll
        for (int r = 0; r < 2; ++r) {
            int o = r * 256 + tid;           // 16B unit index
            int m = o >> 2, slot = o & 3;
            int kc = slot ^ ((m >> 1) & 3);  // stored slot = kc ^ s(m)
            const ushort_t* ga = A  + (size_t)(bm * 128 + m) * I_ + kt * 32 + kc * 8;
            const ushort_t* gb = Bm + (size_t)(bn * 128 + m) * I_ + kt * 32 + kc * 8;
            __builtin_amdgcn_global_load_lds(
                (const __attribute__((address_space(1))) void*)ga,
                (__attribute__((address_space(3))) void*)(&LA[r * 2048 + w * 512]), 16, 0, 0);
            __builtin_amdgcn_global_load_lds(
                (const __attribute__((address_space(1))) void*)gb,
                (__attribute__((address_space(3))) void*)(&LB[r * 2048 + w * 512]), 16, 0, 0);
        }
        __syncthreads();

        short8 av[4], bv[4];
#pragma unroll
        for (int mt = 0; mt < 4; ++mt) {
            int mm = wr * 64 + mt * 16 + l16;
            av[mt] = *(const short8*)&LA[mm * 32 + ((quad ^ ((mm >> 1) & 3)) << 3)];
            int nn = wc * 64 + mt * 16 + l16;
            bv[mt] = *(const short8*)&LB[nn * 32 + ((quad ^ ((nn >> 1) & 3)) << 3)];
        }
#pragma unroll
        for (int mt = 0; mt < 4; ++mt)
#pragma unroll
            for (int nt = 0; nt < 4; ++nt)
                acc[mt][nt] = __builtin_amdgcn_mfma_f32_16x16x32_bf16(av[mt], bv[nt], acc[mt][nt], 0, 0, 0);
        __syncthreads();
    }

#pragma unroll
    for (int nt = 0; nt < 4; ++nt) {
        int n = bn * 128 + wc * 64 + nt * 16 + l16;      // logical gate-space column
        int gate = n >> 9, jj = (n >> 4) & 31, d = n & 15;
        int np = jj * 64 + gate * 16 + d;                // swizzled storage column
        float bvl = bias[n];
#pragma unroll
        for (int mt = 0; mt < 4; ++mt) {
#pragma unroll
            for (int rg = 0; rg < 4; ++rg) {
                int m = bm * 128 + wr * 64 + mt * 16 + quad * 4 + rg;
                C[(size_t)m * G_ + np] = f2bf(acc[mt][nt][rg] + bvl);
            }
        }
    }
}

// ---------- recurrence ----------
// 256 blocks = 8 groups x 32 blocks, ONE BLOCK PER CU, group = blockIdx & 7.
// Rationale: blocks dispatch round-robin over the 8 XCDs (blockIdx%8 == XCD — the same
// mapping the XCD-swizzle technique relies on), so all 32 members of a group share one
// XCD's L2. Group g: batches g*4..g*4+3, chains 0-3 fwd, 4-7 bwd (8 chains). Block
// j = blockIdx>>3 owns h-dims [j*16,+16); wave w = gate section, Wh section in VGPRs.
//
// ROUND 2-5 EVIDENCE: agent-scope exchange runs through the fabric (WRITE_SIZE includes
// the full 64MB hg stream; hg re-fetch ~245MB) with ~2+us store-to-visible latency that
// is insensitive to poll rate (sleep backoff: neutral) and poll size (round 4: worse).
// The fix must remove the fabric from the critical path.
//
// DUAL-PUBLISH exchange, tag-in-data (8B unit = {tag:32 | h_odd:bf16 | h_even:bf16}):
//  - FAST buffer: plain global_store_dwordx2 -> producer XCD's write-back L2. Consumers
//    poll with inline-asm 'sc0' loads (bypass L1, read L2). If the group is co-located,
//    visibility is one L2 write (~100-200cy), never touching the fabric.
//  - AGENT buffer: the round-2-proven __hip_atomic AGENT store/load path. Consumers fall
//    back to it after 64 failed fast sweeps. This keeps CORRECTNESS independent of the
//    (formally undefined) block->XCD mapping: wrong placement = slow, never wrong/hung.
// Tags make both paths tear-safe (8B stores don't tear; each 8B half of a 16B load is
// checked independently) and replay-safe ('>=' + spin caps: stale state from rocprof
// replay exits on the first check; any protocol bug = wrong answer, not a hang).
__global__ __launch_bounds__(256, 1) void krec(const ushort_t* __restrict__ gx,
                                               const ushort_t* __restrict__ whb,
                                               unsigned long long* __restrict__ hgf,
                                               unsigned long long* __restrict__ hga,
                                               float* __restrict__ out) {
    __shared__ __align__(16) ushort_t hl[16 * 520];   // h tile, padded stride (rows 8-15 stay 0)
    __shared__ float gates[4][16][16];                // [gate][chain][dim]
    const int tid = threadIdx.x;
    const int lane = tid & 63, w = tid >> 6;
    const int quad = lane >> 4, l16 = lane & 15;
    const int bk = blockIdx.x, grp = bk & 7, j = bk >> 3;   // group = XCD (round-robin)

    // zero hl once: MFMA A-frags read all 16 rows; rows 8-15 are never written in the loop.
    for (int t = tid; t < (16 * 520) / 2; t += 256) ((uint32_t*)hl)[t] = 0;

    // Wh B-frags for this wave's gate section, cols j*16..+16 (rows of Wh = gate outputs)
    short8 bw[16];
    {
        const ushort_t* wp = whb + (size_t)(w * H_ + j * 16 + l16) * H_ + quad * 8;
#pragma unroll
        for (int kc = 0; kc < 16; ++kc) bw[kc] = *(const short8*)(wp + kc * 32);
    }

    const int r = tid >> 4, d = tid & 15;     // consumer role: r in 0..15, d in 0..15
    const int rr = r & 7, half = r >> 3;      // chain, coverage-half for polling
    const bool cell = (tid < 128);            // cell-update threads: chain r (0..7), dim d
    const int b = grp * 4 + (r & 3), dir = (r >> 2) & 1;
    float c = 0.0f;                           // cell state in register

    unsigned long long* hgrpF = hgf + (size_t)grp * 4096;   // fast: 2 parities x 2048 units
    unsigned long long* hgrpA = hga + (size_t)grp * 4096;   // agent fallback: same layout

    // Thread polls 8 units: u = rr*256 + half*128 + cc*64 + d*4 + k (cc=0..1, k=0..3).
    // Bijective over the 2048-unit parity buffer across the 256 threads.
    const int base0 = rr * 256 + half * 128 + d * 4;

    for (int n = 0; n < 512; ++n) {
        // ---- prefetch gx for this step (independent of h, overlaps the poll) ----
        ushort_t g0 = 0, g1 = 0, g2 = 0, g3 = 0;
        if (cell) {
            int te = dir ? (511 - n) : n;
            const ushort_t* gp = gx + (size_t)(b * T_ + te) * G_ + j * 64 + d;
            g0 = gp[0]; g1 = gp[16]; g2 = gp[32]; g3 = gp[48];
        }

        const uint32_t un = (uint32_t)n;
        uint32_t pay[8];

        // ---- FAST poll: sc0 (L1-bypass, L2-read) 16B loads, tags at dwords y/w ----
        {
            const unsigned long long* f0 = hgrpF + (size_t)(n & 1) * 2048 + base0;
            const void* p0 = (const void*)(f0);
            const void* p1 = (const void*)(f0 + 2);
            const void* p2 = (const void*)(f0 + 64);
            const void* p3 = (const void*)(f0 + 66);
            uint4 u0, u1, u2, u3;
            bool got = false;
            for (int spin = 0; spin < 64; ++spin) {
                asm volatile(
                    "global_load_dwordx4 %0, %4, off sc0\n\t"
                    "global_load_dwordx4 %1, %5, off sc0\n\t"
                    "global_load_dwordx4 %2, %6, off sc0\n\t"
                    "global_load_dwordx4 %3, %7, off sc0\n\t"
                    "s_waitcnt vmcnt(0)"
                    : "=&v"(u0), "=&v"(u1), "=&v"(u2), "=&v"(u3)
                    : "v"(p0), "v"(p1), "v"(p2), "v"(p3)
                    : "memory");
                if (u0.y >= un && u0.w >= un && u1.y >= un && u1.w >= un &&
                    u2.y >= un && u2.w >= un && u3.y >= un && u3.w >= un) { got = true; break; }
            }
            if (got) {
                pay[0] = u0.x; pay[1] = u0.z; pay[2] = u1.x; pay[3] = u1.z;
                pay[4] = u2.x; pay[5] = u2.z; pay[6] = u3.x; pay[7] = u3.z;
            } else {
                // ---- AGENT fallback (round-2-proven path), sleep-throttled ----
                const unsigned long long* a0 = hgrpA + (size_t)(n & 1) * 2048 + base0;
                unsigned long long tv[8];
                for (int spin = 0; spin < 4000; ++spin) {
#pragma unroll
                    for (int i = 0; i < 8; ++i)
                        tv[i] = __hip_atomic_load(a0 + (i >> 2) * 64 + (i & 3),
                                                  __ATOMIC_RELAXED, __HIP_MEMORY_SCOPE_AGENT);
                    bool ok = true;
#pragma unroll
                    for (int i = 0; i < 8; ++i)
                        ok &= ((uint32_t)(tv[i] >> 32) >= un);
                    if (ok) break;
                    __builtin_amdgcn_s_sleep(4);
                }
#pragma unroll
                for (int i = 0; i < 8; ++i) pay[i] = (uint32_t)tv[i];
            }
        }

        // ---- unpack to LDS: 2x ds_write_b128 per thread ----
#pragma unroll
        for (int cc = 0; cc < 2; ++cc) {
            uint4 pk;
            pk.x = pay[cc * 4 + 0];
            pk.y = pay[cc * 4 + 1];
            pk.z = pay[cc * 4 + 2];
            pk.w = pay[cc * 4 + 3];
            *(uint4*)&hl[rr * 520 + half * 256 + cc * 128 + d * 8] = pk;
        }
        __syncthreads();

        // ---- gates = h @ Wh_section^T (two independent MFMA chains) ----
        f32x4 acc0 = {}, acc1 = {};
#pragma unroll
        for (int kc = 0; kc < 16; kc += 2) {
            short8 av0 = *(const short8*)&hl[l16 * 520 + kc * 32 + quad * 8];
            acc0 = __builtin_amdgcn_mfma_f32_16x16x32_bf16(av0, bw[kc], acc0, 0, 0, 0);
            short8 av1 = *(const short8*)&hl[l16 * 520 + (kc + 1) * 32 + quad * 8];
            acc1 = __builtin_amdgcn_mfma_f32_16x16x32_bf16(av1, bw[kc + 1], acc1, 0, 0, 0);
        }
        f32x4 acc = acc0 + acc1;
#pragma unroll
        for (int rg = 0; rg < 4; ++rg) gates[w][quad * 4 + rg][l16] = acc[rg];
        __syncthreads();

        // ---- cell update: thread -> (chain r, dim d), chains 0..7 only ----
        if (cell) {
            float gi = gates[0][r][d] + bf2f(g0);
            float gf = gates[1][r][d] + bf2f(g1);
            float gg = gates[2][r][d] + bf2f(g2);
            float go = gates[3][r][d] + bf2f(g3);
            float it = sigm(gi), ft = sigm(gf), gt = tanhx(gg), ot = sigm(go);
            c = c * ft + it * gt;
            float h = ot * tanhx(c);

            // ---- pack pair + tag, dual-publish to parity (n+1)&1 ----
            int hv = (int)f2bf(h);
            int vo = __shfl(hv, lane ^ 1);
            if (!(d & 1)) {
                uint32_t payv = (((uint32_t)vo & 0xFFFFu) << 16) | ((uint32_t)hv & 0xFFFFu);
                unsigned long long unit = ((unsigned long long)(uint32_t)(n + 1) << 32) | payv;
                size_t u = (size_t)((n + 1) & 1) * 2048 + (size_t)r * 256 + j * 8 + (d >> 1);
                // fast: plain write-back store into local L2
                uint2 uv; uv.x = payv; uv.y = (uint32_t)(n + 1);
                asm volatile("global_store_dwordx2 %0, %1, off"
                             :: "v"((void*)(hgrpF + u)), "v"(uv) : "memory");
                // backstop: agent-scope write-through (fabric)
                __hip_atomic_store(hgrpA + u, unit, __ATOMIC_RELAXED, __HIP_MEMORY_SCOPE_AGENT);
            }
            out[(size_t)b * (T_ * 2 * H_) + (size_t)n * (2 * H_) + dir * H_ + j * 16 + d] = h;
        }
    }
}

// ---------- workspace layout (bytes) ----------
// HGF/HGA alias XB: xb is dead after kgemm; the memset is issued after kgemm in-stream.
#define GX_OFF    ((size_t)0)                    // 16384*2048*2 = 67108864
#define XB_OFF    ((size_t)67108864)             // 16384*512*2 = 16777216
#define HGF_OFF   XB_OFF                         // 8 grp * 2 par * 2048 units * 8B = 262144
#define HGA_OFF   (XB_OFF + 262144)              // same size
#define HG_BYTES  ((size_t)524288)
#define WXB_OFF   ((size_t)83886080)             // 2048*512*2  = 2097152
#define WHB_OFF   ((size_t)85983232)             // 2048*512*2  = 2097152
#define BIAS_OFF  ((size_t)88080384)             // 2048*4      = 8192
#define WS_NEED   ((size_t)88088576)

extern "C" void kernel_launch(void* const* d_in, const int* in_sizes, int n_in,
                              void* d_out, int out_size, void* d_ws, size_t ws_size,
                              hipStream_t stream) {
    if (ws_size < WS_NEED) return;

    const float* x  = (const float*)d_in[0];
    const float* Wx = (const float*)d_in[1];
    const float* bx = (const float*)d_in[2];
    const float* Wh = (const float*)d_in[3];
    const float* bh = (const float*)d_in[4];
    float* out = (float*)d_out;
    char* ws = (char*)d_ws;

    ushort_t* gx   = (ushort_t*)(ws + GX_OFF);
    ushort_t* xb   = (ushort_t*)(ws + XB_OFF);
    ushort_t* wxb  = (ushort_t*)(ws + WXB_OFF);
    ushort_t* whb  = (ushort_t*)(ws + WHB_OFF);
    float*    bias = (float*)(ws + BIAS_OFF);
    unsigned long long* hgf = (unsigned long long*)(ws + HGF_OFF);
    unsigned long long* hga = (unsigned long long*)(ws + HGA_OFF);

    // casts
    kcast<<<dim3((B_ * T_ * I_ / 4 + 255) / 256), 256, 0, stream>>>(x, xb, B_ * T_ * I_ / 4);
    kcast<<<dim3((G_ * I_ / 4 + 255) / 256), 256, 0, stream>>>(Wx, wxb, G_ * I_ / 4);
    kcast<<<dim3((G_ * H_ / 4 + 255) / 256), 256, 0, stream>>>(Wh, whb, G_ * H_ / 4);
    kbias<<<dim3(G_ / 256), 256, 0, stream>>>(bx, bh, bias);

    // input projection GEMM: grid (N/128, M/128) = (16, 128)
    kgemm<<<dim3(G_ / 128, (B_ * T_) / 128), 256, 0, stream>>>(xb, wxb, bias, gx);

    // zero tagged h double-buffers (tag 0 == valid initial state for step 0).
    // Must run after kgemm: HGF/HGA alias the then-dead xb region.
    hipMemsetAsync(ws + HGF_OFF, 0, HG_BYTES, stream);

    // recurrence: 256 persistent blocks (8 groups x 32), one per CU, group = XCD
    krec<<<dim3(256), 256, 0, stream>>>(gx, whb, hgf, hga, out);
}

// Round 8
// 1789.062 us; speedup vs baseline: 2.4576x; 2.4576x over previous
//
#include <hip/hip_runtime.h>
#include <stdint.h>

typedef unsigned short ushort_t;
typedef float f32x4 __attribute__((ext_vector_type(4)));
typedef short short8 __attribute__((ext_vector_type(8)));

#define B_ 32
#define T_ 512
#define I_ 512
#define H_ 512
#define G_ 2048   // 4*H

// ---------- helpers ----------
__device__ __forceinline__ ushort_t f2bf(float f) {
    uint32_t u = __float_as_uint(f);
    u += 0x7FFFu + ((u >> 16) & 1u);   // RNE
    return (ushort_t)(u >> 16);
}
__device__ __forceinline__ float bf2f(ushort_t s) {
    return __uint_as_float(((uint32_t)s) << 16);
}
__device__ __forceinline__ float sigm(float x) { return 1.0f / (1.0f + __expf(-x)); }
__device__ __forceinline__ float tanhx(float x) {
    float e = __expf(-2.0f * fabsf(x));
    float t = (1.0f - e) / (1.0f + e);
    return x >= 0.0f ? t : -t;
}

// ---------- cast fp32 -> bf16 (vectorized) ----------
__global__ __launch_bounds__(256) void kcast(const float* __restrict__ in,
                                             ushort_t* __restrict__ out, int n4) {
    int i = blockIdx.x * 256 + threadIdx.x;
    if (i < n4) {
        float4 v = ((const float4*)in)[i];
        ushort4 o;
        o.x = f2bf(v.x); o.y = f2bf(v.y); o.z = f2bf(v.z); o.w = f2bf(v.w);
        ((ushort4*)out)[i] = o;
    }
}

// ---------- bias fold: bias = bx + bh ----------
__global__ __launch_bounds__(256) void kbias(const float* __restrict__ bx,
                                             const float* __restrict__ bh,
                                             float* __restrict__ bias) {
    int i = blockIdx.x * 256 + threadIdx.x;
    if (i < G_) bias[i] = bx[i] + bh[i];
}

// ---------- GEMM: gx[m][n'] = sum_k xb[m][k]*wxb[n][k] + bias[n], bf16 out ----------
// Column layout swizzled for krec: logical n = gate*512 + jj*16 + d  ->  n' = jj*64 + gate*16 + d
// so each recurrence block's per-(b,t) slice is 64 contiguous values.
__global__ __launch_bounds__(256, 2) void kgemm(const ushort_t* __restrict__ A,
                                                const ushort_t* __restrict__ Bm,
                                                const float* __restrict__ bias,
                                                ushort_t* __restrict__ C) {
    __shared__ __align__(16) ushort_t LA[4096];   // [128 rows][32 k] swizzled
    __shared__ __align__(16) ushort_t LB[4096];
    const int tid = threadIdx.x;
    const int lane = tid & 63, w = tid >> 6;
    const int quad = lane >> 4, l16 = lane & 15;
    const int bn = blockIdx.x, bm = blockIdx.y;
    const int wr = w >> 1, wc = w & 1;

    f32x4 acc[4][4] = {};

    for (int kt = 0; kt < 16; ++kt) {
#pragma unroll
        for (int r = 0; r < 2; ++r) {
            int o = r * 256 + tid;           // 16B unit index
            int m = o >> 2, slot = o & 3;
            int kc = slot ^ ((m >> 1) & 3);  // stored slot = kc ^ s(m)
            const ushort_t* ga = A  + (size_t)(bm * 128 + m) * I_ + kt * 32 + kc * 8;
            const ushort_t* gb = Bm + (size_t)(bn * 128 + m) * I_ + kt * 32 + kc * 8;
            __builtin_amdgcn_global_load_lds(
                (const __attribute__((address_space(1))) void*)ga,
                (__attribute__((address_space(3))) void*)(&LA[r * 2048 + w * 512]), 16, 0, 0);
            __builtin_amdgcn_global_load_lds(
                (const __attribute__((address_space(1))) void*)gb,
                (__attribute__((address_space(3))) void*)(&LB[r * 2048 + w * 512]), 16, 0, 0);
        }
        __syncthreads();

        short8 av[4], bv[4];
#pragma unroll
        for (int mt = 0; mt < 4; ++mt) {
            int mm = wr * 64 + mt * 16 + l16;
            av[mt] = *(const short8*)&LA[mm * 32 + ((quad ^ ((mm >> 1) & 3)) << 3)];
            int nn = wc * 64 + mt * 16 + l16;
            bv[mt] = *(const short8*)&LB[nn * 32 + ((quad ^ ((nn >> 1) & 3)) << 3)];
        }
#pragma unroll
        for (int mt = 0; mt < 4; ++mt)
#pragma unroll
            for (int nt = 0; nt < 4; ++nt)
                acc[mt][nt] = __builtin_amdgcn_mfma_f32_16x16x32_bf16(av[mt], bv[nt], acc[mt][nt], 0, 0, 0);
        __syncthreads();
    }

#pragma unroll
    for (int nt = 0; nt < 4; ++nt) {
        int n = bn * 128 + wc * 64 + nt * 16 + l16;      // logical gate-space column
        int gate = n >> 9, jj = (n >> 4) & 31, d = n & 15;
        int np = jj * 64 + gate * 16 + d;                // swizzled storage column
        float bvl = bias[n];
#pragma unroll
        for (int mt = 0; mt < 4; ++mt) {
#pragma unroll
            for (int rg = 0; rg < 4; ++rg) {
                int m = bm * 128 + wr * 64 + mt * 16 + quad * 4 + rg;
                C[(size_t)m * G_ + np] = f2bf(acc[mt][nt][rg] + bvl);
            }
        }
    }
}

// ---------- recurrence ----------
// 256 blocks, 1/CU. Groups of 32 are built from the HARDWARE XCD id, read with the
// SYMBOLIC hwreg name (assembler-validated for gfx950; numeric id 20 in round 7 was a
// guess and is the prime suspect for the container death). Every block publishes
// (xcd, bk) agent-scope; every thread waits only for ITS OWN entry (so all blocks see
// the same complete table); rank = lexicographic position of (xcd, bk) -> grp = rank>>5,
// j = rank&31. If every XCD hosts exactly 32 blocks, sorted rank makes every group
// XCD-PURE by construction; otherwise pure=false for everyone (consistent) and all
// groups use the proven agent path.
//
// Group g: batches g*4..g*4+3, chains 0-3 fwd, 4-7 bwd. Block j owns h-dims [j*16,+16);
// wave w = gate section, Wh section in VGPRs. Groups independent (disjoint batches).
//
// Exchange, tag-in-data (8B unit = {tag:32 | h_odd:bf16 | h_even:bf16}, memset-0 = valid
// step-0 state), dual-publish every step:
//  - FAST: plain global_store_dwordx2 -> own-XCD write-back L2; consumers sc0-poll
//    (L1-bypass, L2-read). Pure group => producer/consumer share one physical L2 =>
//    visibility ~150cy, fabric off the critical path.
//  - AGENT backstop: round-2/4-proven __hip_atomic AGENT store + poll. Used by impure
//    groups and on fast-poll timeout. Correctness independent of placement/mechanism.
// Poll predicate (tag >= n): == in live runs (producer reaches tag n+2 only after all
// blocks exited poll(n)); instant-exit under rocprof replay against stale state.
// WORST-CASE BOUNDS (all spins capped): roster ~20ms, per-step fallback 600 spins
// (~0.35ms) -> absolute worst ~180ms/dispatch with wrong answer — NEVER a hang.
__global__ __launch_bounds__(256, 1) void krec(const ushort_t* __restrict__ gx,
                                               const ushort_t* __restrict__ whb,
                                               unsigned long long* __restrict__ hgf,
                                               unsigned long long* __restrict__ hga,
                                               uint32_t* __restrict__ xtab,
                                               float* __restrict__ out) {
    __shared__ __align__(16) ushort_t hl[16 * 520];   // h tile, padded stride (rows 8-15 stay 0)
    __shared__ float gates[4][16][16];                // [gate][chain][dim]
    __shared__ uint32_t sx[256];
    __shared__ int s_grp, s_j, s_pure;
    const int tid = threadIdx.x;
    const int lane = tid & 63, w = tid >> 6;
    const int quad = lane >> 4, l16 = lane & 15;
    const int bk = blockIdx.x;

    // zero hl once: MFMA A-frags read all 16 rows; rows 8-15 are never written in the loop.
    for (int t = tid; t < (16 * 520) / 2; t += 256) ((uint32_t*)hl)[t] = 0;

    // ---- roster: discover XCD (symbolic hwreg), publish, build assignment ----
    uint32_t xcd;
    asm("s_getreg_b32 %0, hwreg(HW_REG_XCC_ID)" : "=s"(xcd));
    xcd &= 7u;
    if (tid == 0)
        __hip_atomic_store(&xtab[bk], 0x100u | xcd, __ATOMIC_RELAXED, __HIP_MEMORY_SCOPE_AGENT);
    {
        uint32_t e = 0;
        for (int spin = 0; spin < (1 << 16); ++spin) {   // ~20ms cap
            e = __hip_atomic_load(&xtab[tid], __ATOMIC_RELAXED, __HIP_MEMORY_SCOPE_AGENT);
            if (e & 0x100u) break;
            __builtin_amdgcn_s_sleep(8);
        }
        sx[tid] = e;   // keep valid bit for the strict purity check
    }
    __syncthreads();
    if (tid == 0) {
        int cnt[8] = {0,0,0,0,0,0,0,0};
        int allvalid = 1;
        for (int i = 0; i < 256; ++i) {
            if (!(sx[i] & 0x100u)) allvalid = 0;
            cnt[sx[i] & 7u]++;
        }
        int balanced = allvalid;
        for (int x = 0; x < 8; ++x) if (cnt[x] != 32) balanced = 0;
        int pre[9]; pre[0] = 0;
        for (int x = 0; x < 8; ++x) pre[x + 1] = pre[x] + cnt[x];
        int rank = pre[xcd];
        for (int i = 0; i < bk; ++i) if ((sx[i] & 7u) == xcd) rank++;
        s_grp = rank >> 5; s_j = rank & 31; s_pure = balanced;
    }
    __syncthreads();
    const int grp = s_grp, j = s_j;
    const bool pure = (s_pure != 0);

    // Wh B-frags for this wave's gate section, cols j*16..+16 (rows of Wh = gate outputs)
    short8 bw[16];
    {
        const ushort_t* wp = whb + (size_t)(w * H_ + j * 16 + l16) * H_ + quad * 8;
#pragma unroll
        for (int kc = 0; kc < 16; ++kc) bw[kc] = *(const short8*)(wp + kc * 32);
    }

    const int r = tid >> 4, d = tid & 15;     // consumer role: r in 0..15, d in 0..15
    const int rr = r & 7, half = r >> 3;      // chain, coverage-half for polling
    const bool cell = (tid < 128);            // cell-update threads: chain r (0..7), dim d
    const int b = grp * 4 + (r & 3), dir = (r >> 2) & 1;
    float c = 0.0f;                           // cell state in register

    unsigned long long* hgrpF = hgf + (size_t)grp * 4096;   // fast: 2 parities x 2048 units
    unsigned long long* hgrpA = hga + (size_t)grp * 4096;   // agent backstop: same layout

    // Thread polls 8 units: base0 + {0..3} and base0 + 64 + {0..3}.
    // Bijective over the 2048-unit parity buffer across the 256 threads.
    const int base0 = rr * 256 + half * 128 + d * 4;

    for (int n = 0; n < 512; ++n) {
        // ---- prefetch gx for this step (independent of h, overlaps the poll) ----
        ushort_t g0 = 0, g1 = 0, g2 = 0, g3 = 0;
        if (cell) {
            int te = dir ? (511 - n) : n;
            const ushort_t* gp = gx + (size_t)(b * T_ + te) * G_ + j * 64 + d;
            g0 = gp[0]; g1 = gp[16]; g2 = gp[32]; g3 = gp[48];
        }

        const uint32_t un = (uint32_t)n;
        uint32_t pay[8];
        bool got = false;

        // ---- FAST poll (pure groups): sc0 16B loads from the shared XCD L2 ----
        if (pure) {
            const unsigned long long* f0 = hgrpF + (size_t)(n & 1) * 2048 + base0;
            const void* p0 = (const void*)(f0);
            const void* p1 = (const void*)(f0 + 2);
            const void* p2 = (const void*)(f0 + 64);
            const void* p3 = (const void*)(f0 + 66);
            uint4 u0, u1, u2, u3;
            for (int spin = 0; spin < 16; ++spin) {
                asm volatile(
                    "global_load_dwordx4 %0, %4, off sc0\n\t"
                    "global_load_dwordx4 %1, %5, off sc0\n\t"
                    "global_load_dwordx4 %2, %6, off sc0\n\t"
                    "global_load_dwordx4 %3, %7, off sc0\n\t"
                    "s_waitcnt vmcnt(0)"
                    : "=&v"(u0), "=&v"(u1), "=&v"(u2), "=&v"(u3)
                    : "v"(p0), "v"(p1), "v"(p2), "v"(p3)
                    : "memory");
                if (u0.y >= un && u0.w >= un && u1.y >= un && u1.w >= un &&
                    u2.y >= un && u2.w >= un && u3.y >= un && u3.w >= un) { got = true; break; }
            }
            if (got) {
                pay[0] = u0.x; pay[1] = u0.z; pay[2] = u1.x; pay[3] = u1.z;
                pay[4] = u2.x; pay[5] = u2.z; pay[6] = u3.x; pay[7] = u3.z;
            }
        }
        if (!got) {
            // ---- AGENT backstop (round-2/4-proven), sleep-throttled, tight cap ----
            const unsigned long long* a0 = hgrpA + (size_t)(n & 1) * 2048 + base0;
            unsigned long long tv[8];
            for (int spin = 0; spin < 600; ++spin) {
#pragma unroll
                for (int i = 0; i < 8; ++i)
                    tv[i] = __hip_atomic_load(a0 + (i >> 2) * 64 + (i & 3),
                                              __ATOMIC_RELAXED, __HIP_MEMORY_SCOPE_AGENT);
                bool ok = true;
#pragma unroll
                for (int i = 0; i < 8; ++i)
                    ok &= ((uint32_t)(tv[i] >> 32) >= un);
                if (ok) break;
                __builtin_amdgcn_s_sleep(4);
            }
#pragma unroll
            for (int i = 0; i < 8; ++i) pay[i] = (uint32_t)tv[i];
        }

        // ---- unpack to LDS: 2x ds_write_b128 per thread ----
#pragma unroll
        for (int cc = 0; cc < 2; ++cc) {
            uint4 pk;
            pk.x = pay[cc * 4 + 0];
            pk.y = pay[cc * 4 + 1];
            pk.z = pay[cc * 4 + 2];
            pk.w = pay[cc * 4 + 3];
            *(uint4*)&hl[rr * 520 + half * 256 + cc * 128 + d * 8] = pk;
        }
        __syncthreads();

        // ---- gates = h @ Wh_section^T (two independent MFMA chains) ----
        f32x4 acc0 = {}, acc1 = {};
#pragma unroll
        for (int kc = 0; kc < 16; kc += 2) {
            short8 av0 = *(const short8*)&hl[l16 * 520 + kc * 32 + quad * 8];
            acc0 = __builtin_amdgcn_mfma_f32_16x16x32_bf16(av0, bw[kc], acc0, 0, 0, 0);
            short8 av1 = *(const short8*)&hl[l16 * 520 + (kc + 1) * 32 + quad * 8];
            acc1 = __builtin_amdgcn_mfma_f32_16x16x32_bf16(av1, bw[kc + 1], acc1, 0, 0, 0);
        }
        f32x4 acc = acc0 + acc1;
#pragma unroll
        for (int rg = 0; rg < 4; ++rg) gates[w][quad * 4 + rg][l16] = acc[rg];
        __syncthreads();

        // ---- cell update: thread -> (chain r, dim d), chains 0..7 only ----
        if (cell) {
            float gi = gates[0][r][d] + bf2f(g0);
            float gf = gates[1][r][d] + bf2f(g1);
            float gg = gates[2][r][d] + bf2f(g2);
            float go = gates[3][r][d] + bf2f(g3);
            float it = sigm(gi), ft = sigm(gf), gt = tanhx(gg), ot = sigm(go);
            c = c * ft + it * gt;
            float h = ot * tanhx(c);

            // ---- pack pair + tag, dual-publish to parity (n+1)&1 ----
            int hv = (int)f2bf(h);
            int vo = __shfl(hv, lane ^ 1);
            if (!(d & 1)) {
                uint32_t payv = (((uint32_t)vo & 0xFFFFu) << 16) | ((uint32_t)hv & 0xFFFFu);
                unsigned long long unit = ((unsigned long long)(uint32_t)(n + 1) << 32) | payv;
                size_t u = (size_t)((n + 1) & 1) * 2048 + (size_t)r * 256 + j * 8 + (d >> 1);
                // fast: plain write-back store into the group's (own-XCD) L2
                uint2 uv; uv.x = payv; uv.y = (uint32_t)(n + 1);
                asm volatile("global_store_dwordx2 %0, %1, off"
                             :: "v"((void*)(hgrpF + u)), "v"(uv) : "memory");
                // backstop: agent-scope write-through (fabric)
                __hip_atomic_store(hgrpA + u, unit, __ATOMIC_RELAXED, __HIP_MEMORY_SCOPE_AGENT);
            }
            out[(size_t)b * (T_ * 2 * H_) + (size_t)n * (2 * H_) + dir * H_ + j * 16 + d] = h;
        }
    }
}

// ---------- workspace layout (bytes) ----------
// HGF/HGA/XTAB alias XB: xb is dead after kgemm; the memset is issued after kgemm in-stream.
#define GX_OFF    ((size_t)0)                    // 16384*2048*2 = 67108864
#define XB_OFF    ((size_t)67108864)             // 16384*512*2 = 16777216
#define HGF_OFF   XB_OFF                         // 8 grp * 2 par * 2048 units * 8B = 262144
#define HGA_OFF   (XB_OFF + 262144)              // same size
#define XTAB_OFF  (XB_OFF + 524288)              // 256 * 4 = 1024
#define HG_BYTES  ((size_t)(524288 + 1024))
#define WXB_OFF   ((size_t)83886080)             // 2048*512*2  = 2097152
#define WHB_OFF   ((size_t)85983232)             // 2048*512*2  = 2097152
#define BIAS_OFF  ((size_t)88080384)             // 2048*4      = 8192
#define WS_NEED   ((size_t)88088576)

extern "C" void kernel_launch(void* const* d_in, const int* in_sizes, int n_in,
                              void* d_out, int out_size, void* d_ws, size_t ws_size,
                              hipStream_t stream) {
    if (ws_size < WS_NEED) return;

    const float* x  = (const float*)d_in[0];
    const float* Wx = (const float*)d_in[1];
    const float* bx = (const float*)d_in[2];
    const float* Wh = (const float*)d_in[3];
    const float* bh = (const float*)d_in[4];
    float* out = (float*)d_out;
    char* ws = (char*)d_ws;

    ushort_t* gx   = (ushort_t*)(ws + GX_OFF);
    ushort_t* xb   = (ushort_t*)(ws + XB_OFF);
    ushort_t* wxb  = (ushort_t*)(ws + WXB_OFF);
    ushort_t* whb  = (ushort_t*)(ws + WHB_OFF);
    float*    bias = (float*)(ws + BIAS_OFF);
    unsigned long long* hgf = (unsigned long long*)(ws + HGF_OFF);
    unsigned long long* hga = (unsigned long long*)(ws + HGA_OFF);
    uint32_t* xtab = (uint32_t*)(ws + XTAB_OFF);

    // casts
    kcast<<<dim3((B_ * T_ * I_ / 4 + 255) / 256), 256, 0, stream>>>(x, xb, B_ * T_ * I_ / 4);
    kcast<<<dim3((G_ * I_ / 4 + 255) / 256), 256, 0, stream>>>(Wx, wxb, G_ * I_ / 4);
    kcast<<<dim3((G_ * H_ / 4 + 255) / 256), 256, 0, stream>>>(Wh, whb, G_ * H_ / 4);
    kbias<<<dim3(G_ / 256), 256, 0, stream>>>(bx, bh, bias);

    // input projection GEMM: grid (N/128, M/128) = (16, 128)
    kgemm<<<dim3(G_ / 128, (B_ * T_) / 128), 256, 0, stream>>>(xb, wxb, bias, gx);

    // zero tagged h double-buffers + roster table (tag 0 == valid initial state).
    // Must run after kgemm: they alias the then-dead xb region.
    hipMemsetAsync(ws + HGF_OFF, 0, HG_BYTES, stream);

    // recurrence: 256 persistent blocks (8 XCD-pure groups x 32), one per CU
    krec<<<dim3(256), 256, 0, stream>>>(gx, whb, hgf, hga, xtab, out);
}

// Round 10
// 1126.702 us; speedup vs baseline: 3.9023x; 1.5879x over previous
//
#include <hip/hip_runtime.h>
#include <stdint.h>

typedef unsigned short ushort_t;
typedef float f32x4 __attribute__((ext_vector_type(4)));
typedef short short8 __attribute__((ext_vector_type(8)));

#define B_ 32
#define T_ 512
#define I_ 512
#define H_ 512
#define G_ 2048   // 4*H

// ---------- helpers ----------
__device__ __forceinline__ ushort_t f2bf(float f) {
    uint32_t u = __float_as_uint(f);
    u += 0x7FFFu + ((u >> 16) & 1u);   // RNE
    return (ushort_t)(u >> 16);
}
__device__ __forceinline__ float bf2f(ushort_t s) {
    return __uint_as_float(((uint32_t)s) << 16);
}
__device__ __forceinline__ float sigm(float x) { return 1.0f / (1.0f + __expf(-x)); }
__device__ __forceinline__ float tanhx(float x) {
    float e = __expf(-2.0f * fabsf(x));
    float t = (1.0f - e) / (1.0f + e);
    return x >= 0.0f ? t : -t;
}

// ---------- cast fp32 -> bf16 (vectorized) ----------
__global__ __launch_bounds__(256) void kcast(const float* __restrict__ in,
                                             ushort_t* __restrict__ out, int n4) {
    int i = blockIdx.x * 256 + threadIdx.x;
    if (i < n4) {
        float4 v = ((const float4*)in)[i];
        ushort4 o;
        o.x = f2bf(v.x); o.y = f2bf(v.y); o.z = f2bf(v.z); o.w = f2bf(v.w);
        ((ushort4*)out)[i] = o;
    }
}

// ---------- bias fold: bias = bx + bh ----------
__global__ __launch_bounds__(256) void kbias(const float* __restrict__ bx,
                                             const float* __restrict__ bh,
                                             float* __restrict__ bias) {
    int i = blockIdx.x * 256 + threadIdx.x;
    if (i < G_) bias[i] = bx[i] + bh[i];
}

// ---------- GEMM: gx[m][n'] = sum_k xb[m][k]*wxb[n][k] + bias[n], bf16 out ----------
// Column layout swizzled for krec: logical n = gate*512 + jj*16 + d  ->  n' = jj*64 + gate*16 + d
// so each recurrence block's per-(b,t) slice is 64 contiguous values.
__global__ __launch_bounds__(256, 2) void kgemm(const ushort_t* __restrict__ A,
                                                const ushort_t* __restrict__ Bm,
                                                const float* __restrict__ bias,
                                                ushort_t* __restrict__ C) {
    __shared__ __align__(16) ushort_t LA[4096];   // [128 rows][32 k] swizzled
    __shared__ __align__(16) ushort_t LB[4096];
    const int tid = threadIdx.x;
    const int lane = tid & 63, w = tid >> 6;
    const int quad = lane >> 4, l16 = lane & 15;
    const int bn = blockIdx.x, bm = blockIdx.y;
    const int wr = w >> 1, wc = w & 1;

    f32x4 acc[4][4] = {};

    for (int kt = 0; kt < 16; ++kt) {
#pragma unroll
        for (int r = 0; r < 2; ++r) {
            int o = r * 256 + tid;           // 16B unit index
            int m = o >> 2, slot = o & 3;
            int kc = slot ^ ((m >> 1) & 3);  // stored slot = kc ^ s(m)
            const ushort_t* ga = A  + (size_t)(bm * 128 + m) * I_ + kt * 32 + kc * 8;
            const ushort_t* gb = Bm + (size_t)(bn * 128 + m) * I_ + kt * 32 + kc * 8;
            __builtin_amdgcn_global_load_lds(
                (const __attribute__((address_space(1))) void*)ga,
                (__attribute__((address_space(3))) void*)(&LA[r * 2048 + w * 512]), 16, 0, 0);
            __builtin_amdgcn_global_load_lds(
                (const __attribute__((address_space(1))) void*)gb,
                (__attribute__((address_space(3))) void*)(&LB[r * 2048 + w * 512]), 16, 0, 0);
        }
        __syncthreads();

        short8 av[4], bv[4];
#pragma unroll
        for (int mt = 0; mt < 4; ++mt) {
            int mm = wr * 64 + mt * 16 + l16;
            av[mt] = *(const short8*)&LA[mm * 32 + ((quad ^ ((mm >> 1) & 3)) << 3)];
            int nn = wc * 64 + mt * 16 + l16;
            bv[mt] = *(const short8*)&LB[nn * 32 + ((quad ^ ((nn >> 1) & 3)) << 3)];
        }
#pragma unroll
        for (int mt = 0; mt < 4; ++mt)
#pragma unroll
            for (int nt = 0; nt < 4; ++nt)
                acc[mt][nt] = __builtin_amdgcn_mfma_f32_16x16x32_bf16(av[mt], bv[nt], acc[mt][nt], 0, 0, 0);
        __syncthreads();
    }

#pragma unroll
    for (int nt = 0; nt < 4; ++nt) {
        int n = bn * 128 + wc * 64 + nt * 16 + l16;      // logical gate-space column
        int gate = n >> 9, jj = (n >> 4) & 31, d = n & 15;
        int np = jj * 64 + gate * 16 + d;                // swizzled storage column
        float bvl = bias[n];
#pragma unroll
        for (int mt = 0; mt < 4; ++mt) {
#pragma unroll
            for (int rg = 0; rg < 4; ++rg) {
                int m = bm * 128 + wr * 64 + mt * 16 + quad * 4 + rg;
                C[(size_t)m * G_ + np] = f2bf(acc[mt][nt][rg] + bvl);
            }
        }
    }
}

// ---------- recurrence ----------
// 256 blocks, 1/CU. Groups of 32 built from the HARDWARE XCD id (symbolic
// hwreg(HW_REG_XCC_ID), proven round 8): publish (xcd, bk) agent-scope, rank =
// lexicographic position -> grp = rank>>5, j = rank&31; balanced (32 blocks/XCD) =>
// every group is XCD-pure by construction. A second roster phase takes a global
// AND-VOTE on purity so all 256 blocks commit to the SAME mode (kills the divergent
// pure/impure tail risk).
//
// ROUND-9 LESSON: the sc0-asm fast poll goes STALE — on gfx950 sc0 is not old-glc;
// poll loops pin their lines in L1 by LRU and can miss updates indefinitely. Round 8
// only passed because its 16-sweep expiry fell back to the agent path. THIS ROUND the
// pure-mode poll uses AGENT-scope relaxed ATOMIC loads (round-2-proven codegen: bypasses
// L1, reads the LOCAL L2 — round-2 FETCH evidence) pointed at the fast buffer. For an
// XCD-pure group the producer's plain write-back store updates that same physical L2:
// visibility at L2 latency, no L1 staleness possible, NO fabric on either side, and
// nothing slow in the vmcnt queue (pure producers issue no agent stores).
// Impure mode: round-2/4-proven agent dual path, verbatim.
//
// Exchange: tag-in-data, 8B unit = {tag:32 | h_odd:bf16 | h_even:bf16}; memset-0 = valid
// step-0 state. Poll predicate (tag >= n): == in live runs (a producer reaches tag n+2
// only after all blocks exited poll(n)); instant-exit under rocprof replay on stale
// state. All spins capped (roster ~20ms, pure 2048 sweeps, agent 600): any protocol
// failure = bounded-time wrong answer, NEVER a hang.
__global__ __launch_bounds__(256, 1) void krec(const ushort_t* __restrict__ gx,
                                               const ushort_t* __restrict__ whb,
                                               unsigned long long* __restrict__ hgf,
                                               unsigned long long* __restrict__ hga,
                                               uint32_t* __restrict__ xtab,
                                               float* __restrict__ out) {
    __shared__ __align__(16) ushort_t hl[16 * 520];   // h tile, padded stride (rows 8-15 stay 0)
    __shared__ float gates[4][16][16];                // [gate][chain][dim]
    __shared__ uint32_t sx[256];
    __shared__ int s_grp, s_j, s_pure;
    const int tid = threadIdx.x;
    const int lane = tid & 63, w = tid >> 6;
    const int quad = lane >> 4, l16 = lane & 15;
    const int bk = blockIdx.x;

    // zero hl once: MFMA A-frags read all 16 rows; rows 8-15 are never written in the loop.
    for (int t = tid; t < (16 * 520) / 2; t += 256) ((uint32_t*)hl)[t] = 0;

    // ---- roster phase 1: discover XCD, publish, gather, rank ----
    uint32_t xcd;
    asm("s_getreg_b32 %0, hwreg(HW_REG_XCC_ID)" : "=s"(xcd));
    xcd &= 7u;
    if (tid == 0)
        __hip_atomic_store(&xtab[bk], 0x100u | xcd, __ATOMIC_RELAXED, __HIP_MEMORY_SCOPE_AGENT);
    {
        uint32_t e = 0;
        for (int spin = 0; spin < (1 << 16); ++spin) {   // ~20ms cap
            e = __hip_atomic_load(&xtab[tid], __ATOMIC_RELAXED, __HIP_MEMORY_SCOPE_AGENT);
            if (e & 0x100u) break;
            __builtin_amdgcn_s_sleep(8);
        }
        sx[tid] = e;
    }
    __syncthreads();
    if (tid == 0) {
        int cnt[8] = {0,0,0,0,0,0,0,0};
        int allvalid = 1;
        for (int i = 0; i < 256; ++i) {
            if (!(sx[i] & 0x100u)) allvalid = 0;
            cnt[sx[i] & 7u]++;
        }
        int balanced = allvalid;
        for (int x = 0; x < 8; ++x) if (cnt[x] != 32) balanced = 0;
        int pre[9]; pre[0] = 0;
        for (int x = 0; x < 8; ++x) pre[x + 1] = pre[x] + cnt[x];
        int rank = pre[xcd];
        for (int i = 0; i < bk; ++i) if ((sx[i] & 7u) == xcd) rank++;
        s_grp = rank >> 5; s_j = rank & 31;
        // ---- roster phase 2a: publish purity vote ----
        __hip_atomic_store(&xtab[256 + bk], 0x200u | (uint32_t)balanced,
                           __ATOMIC_RELAXED, __HIP_MEMORY_SCOPE_AGENT);
    }
    __syncthreads();
    // ---- roster phase 2b: gather votes, global AND ----
    {
        uint32_t v = 0;
        for (int spin = 0; spin < (1 << 16); ++spin) {
            v = __hip_atomic_load(&xtab[256 + tid], __ATOMIC_RELAXED, __HIP_MEMORY_SCOPE_AGENT);
            if (v & 0x200u) break;
            __builtin_amdgcn_s_sleep(8);
        }
        sx[tid] = (v & 0x200u) ? (v & 1u) : 0u;   // timeout counts as impure vote
    }
    __syncthreads();
    if (tid == 0) {
        int p = 1;
        for (int i = 0; i < 256; ++i) p &= (int)sx[i];
        s_pure = p;
    }
    __syncthreads();
    const int grp = s_grp, j = s_j;
    const bool pure = (s_pure != 0);

    // Wh B-frags for this wave's gate section, cols j*16..+16 (rows of Wh = gate outputs)
    short8 bw[16];
    {
        const ushort_t* wp = whb + (size_t)(w * H_ + j * 16 + l16) * H_ + quad * 8;
#pragma unroll
        for (int kc = 0; kc < 16; ++kc) bw[kc] = *(const short8*)(wp + kc * 32);
    }

    const int r = tid >> 4, d = tid & 15;     // consumer role: r in 0..15, d in 0..15
    const int rr = r & 7, half = r >> 3;      // chain, coverage-half for polling
    const bool cell = (tid < 128);            // cell-update threads: chain r (0..7), dim d
    const int b = grp * 4 + (r & 3), dir = (r >> 2) & 1;
    float c = 0.0f;                           // cell state in register

    unsigned long long* hgrpF = hgf + (size_t)grp * 4096;   // fast: 2 parities x 2048 units
    unsigned long long* hgrpA = hga + (size_t)grp * 4096;   // agent path: same layout

    // Thread polls 8 units: base0 + {0..3} and base0 + 64 + {0..3}.
    // Bijective over the 2048-unit parity buffer across the 256 threads.
    const int base0 = rr * 256 + half * 128 + d * 4;

    for (int n = 0; n < 512; ++n) {
        // ---- prefetch gx for this step (independent of h, overlaps the poll) ----
        ushort_t g0 = 0, g1 = 0, g2 = 0, g3 = 0;
        if (cell) {
            int te = dir ? (511 - n) : n;
            const ushort_t* gp = gx + (size_t)(b * T_ + te) * G_ + j * 64 + d;
            g0 = gp[0]; g1 = gp[16]; g2 = gp[32]; g3 = gp[48];
        }

        const uint32_t un = (uint32_t)n;
        uint32_t pay[8];

        if (pure) {
            // ---- FAST poll: agent-scope ATOMIC loads (L1-bypass, local-L2 read) on the
            //      fast buffer. Producer's plain store updates this same physical L2.
            //      Nothing slow in the vmcnt queue. On cap expiry: proceed (bounded). ----
            const unsigned long long* f0 = hgrpF + (size_t)(n & 1) * 2048 + base0;
            unsigned long long tv[8];
            for (int spin = 0; spin < 2048; ++spin) {
#pragma unroll
                for (int i = 0; i < 8; ++i)
                    tv[i] = __hip_atomic_load(f0 + (i >> 2) * 64 + (i & 3),
                                              __ATOMIC_RELAXED, __HIP_MEMORY_SCOPE_AGENT);
                bool ok = true;
#pragma unroll
                for (int i = 0; i < 8; ++i)
                    ok &= ((uint32_t)(tv[i] >> 32) >= un);
                if (ok) break;
                __builtin_amdgcn_s_sleep(1);   // cut local-L2 poll contention
            }
#pragma unroll
            for (int i = 0; i < 8; ++i) pay[i] = (uint32_t)tv[i];
        } else {
            // ---- AGENT path (round-2/5-proven), sleep-throttled, tight cap ----
            const unsigned long long* a0 = hgrpA + (size_t)(n & 1) * 2048 + base0;
            unsigned long long tv[8];
            for (int spin = 0; spin < 600; ++spin) {
#pragma unroll
                for (int i = 0; i < 8; ++i)
                    tv[i] = __hip_atomic_load(a0 + (i >> 2) * 64 + (i & 3),
                                              __ATOMIC_RELAXED, __HIP_MEMORY_SCOPE_AGENT);
                bool ok = true;
#pragma unroll
                for (int i = 0; i < 8; ++i)
                    ok &= ((uint32_t)(tv[i] >> 32) >= un);
                if (ok) break;
                __builtin_amdgcn_s_sleep(4);
            }
#pragma unroll
            for (int i = 0; i < 8; ++i) pay[i] = (uint32_t)tv[i];
        }

        // ---- unpack to LDS: 2x ds_write_b128 per thread ----
#pragma unroll
        for (int cc = 0; cc < 2; ++cc) {
            uint4 pk;
            pk.x = pay[cc * 4 + 0];
            pk.y = pay[cc * 4 + 1];
            pk.z = pay[cc * 4 + 2];
            pk.w = pay[cc * 4 + 3];
            *(uint4*)&hl[rr * 520 + half * 256 + cc * 128 + d * 8] = pk;
        }
        __syncthreads();

        // ---- gates = h @ Wh_section^T (two independent MFMA chains) ----
        f32x4 acc0 = {}, acc1 = {};
#pragma unroll
        for (int kc = 0; kc < 16; kc += 2) {
            short8 av0 = *(const short8*)&hl[l16 * 520 + kc * 32 + quad * 8];
            acc0 = __builtin_amdgcn_mfma_f32_16x16x32_bf16(av0, bw[kc], acc0, 0, 0, 0);
            short8 av1 = *(const short8*)&hl[l16 * 520 + (kc + 1) * 32 + quad * 8];
            acc1 = __builtin_amdgcn_mfma_f32_16x16x32_bf16(av1, bw[kc + 1], acc1, 0, 0, 0);
        }
        f32x4 acc = acc0 + acc1;
#pragma unroll
        for (int rg = 0; rg < 4; ++rg) gates[w][quad * 4 + rg][l16] = acc[rg];
        __syncthreads();

        // ---- cell update: thread -> (chain r, dim d), chains 0..7 only ----
        if (cell) {
            float gi = gates[0][r][d] + bf2f(g0);
            float gf = gates[1][r][d] + bf2f(g1);
            float gg = gates[2][r][d] + bf2f(g2);
            float go = gates[3][r][d] + bf2f(g3);
            float it = sigm(gi), ft = sigm(gf), gt = tanhx(gg), ot = sigm(go);
            c = c * ft + it * gt;
            float h = ot * tanhx(c);

            // ---- pack pair + tag, publish to parity (n+1)&1 ----
            int hv = (int)f2bf(h);
            int vo = __shfl(hv, lane ^ 1);
            if (!(d & 1)) {
                uint32_t payv = (((uint32_t)vo & 0xFFFFu) << 16) | ((uint32_t)hv & 0xFFFFu);
                size_t u = (size_t)((n + 1) & 1) * 2048 + (size_t)r * 256 + j * 8 + (d >> 1);
                // fast: plain write-back store into the group's (own-XCD) L2
                uint2 uv; uv.x = payv; uv.y = (uint32_t)(n + 1);
                asm volatile("global_store_dwordx2 %0, %1, off"
                             :: "v"((void*)(hgrpF + u)), "v"(uv) : "memory");
                if (!pure) {
                    // impure placement: fabric write-through so agent polls can see it
                    unsigned long long unit =
                        ((unsigned long long)(uint32_t)(n + 1) << 32) | payv;
                    __hip_atomic_store(hgrpA + u, unit,
                                       __ATOMIC_RELAXED, __HIP_MEMORY_SCOPE_AGENT);
                }
            }
            out[(size_t)b * (T_ * 2 * H_) + (size_t)n * (2 * H_) + dir * H_ + j * 16 + d] = h;
        }
    }
}

// ---------- workspace layout (bytes) ----------
// HGF/HGA/XTAB alias XB: xb is dead after kgemm; the memset is issued after kgemm in-stream.
#define GX_OFF    ((size_t)0)                    // 16384*2048*2 = 67108864
#define XB_OFF    ((size_t)67108864)             // 16384*512*2 = 16777216
#define HGF_OFF   XB_OFF                         // 8 grp * 2 par * 2048 units * 8B = 262144
#define HGA_OFF   (XB_OFF + 262144)              // same size
#define XTAB_OFF  (XB_OFF + 524288)              // 512 * 4 = 2048 (roster + votes)
#define HG_BYTES  ((size_t)(524288 + 2048))
#define WXB_OFF   ((size_t)83886080)             // 2048*512*2  = 2097152
#define WHB_OFF   ((size_t)85983232)             // 2048*512*2  = 2097152
#define BIAS_OFF  ((size_t)88080384)             // 2048*4      = 8192
#define WS_NEED   ((size_t)88088576)

extern "C" void kernel_launch(void* const* d_in, const int* in_sizes, int n_in,
                              void* d_out, int out_size, void* d_ws, size_t ws_size,
                              hipStream_t stream) {
    if (ws_size < WS_NEED) return;

    const float* x  = (const float*)d_in[0];
    const float* Wx = (const float*)d_in[1];
    const float* bx = (const float*)d_in[2];
    const float* Wh = (const float*)d_in[3];
    const float* bh = (const float*)d_in[4];
    float* out = (float*)d_out;
    char* ws = (char*)d_ws;

    ushort_t* gx   = (ushort_t*)(ws + GX_OFF);
    ushort_t* xb   = (ushort_t*)(ws + XB_OFF);
    ushort_t* wxb  = (ushort_t*)(ws + WXB_OFF);
    ushort_t* whb  = (ushort_t*)(ws + WHB_OFF);
    float*    bias = (float*)(ws + BIAS_OFF);
    unsigned long long* hgf = (unsigned long long*)(ws + HGF_OFF);
    unsigned long long* hga = (unsigned long long*)(ws + HGA_OFF);
    uint32_t* xtab = (uint32_t*)(ws + XTAB_OFF);

    // casts
    kcast<<<dim3((B_ * T_ * I_ / 4 + 255) / 256), 256, 0, stream>>>(x, xb, B_ * T_ * I_ / 4);
    kcast<<<dim3((G_ * I_ / 4 + 255) / 256), 256, 0, stream>>>(Wx, wxb, G_ * I_ / 4);
    kcast<<<dim3((G_ * H_ / 4 + 255) / 256), 256, 0, stream>>>(Wh, whb, G_ * H_ / 4);
    kbias<<<dim3(G_ / 256), 256, 0, stream>>>(bx, bh, bias);

    // input projection GEMM: grid (N/128, M/128) = (16, 128)
    kgemm<<<dim3(G_ / 128, (B_ * T_) / 128), 256, 0, stream>>>(xb, wxb, bias, gx);

    // zero tagged h double-buffers + roster/vote table (tag 0 == valid initial state).
    // Must run after kgemm: they alias the then-dead xb region.
    hipMemsetAsync(ws + HGF_OFF, 0, HG_BYTES, stream);

    // recurrence: 256 persistent blocks (8 XCD-pure groups x 32), one per CU
    krec<<<dim3(256), 256, 0, stream>>>(gx, whb, hgf, hga, xtab, out);
}

// Round 11
// 954.346 us; speedup vs baseline: 4.6071x; 1.1806x over previous
//
#include <hip/hip_runtime.h>
#include <stdint.h>

typedef unsigned short ushort_t;
typedef float f32x4 __attribute__((ext_vector_type(4)));
typedef short short8 __attribute__((ext_vector_type(8)));

#define B_ 32
#define T_ 512
#define I_ 512
#define H_ 512
#define G_ 2048   // 4*H

// ---------- helpers ----------
__device__ __forceinline__ ushort_t f2bf(float f) {
    uint32_t u = __float_as_uint(f);
    u += 0x7FFFu + ((u >> 16) & 1u);   // RNE
    return (ushort_t)(u >> 16);
}
__device__ __forceinline__ float bf2f(ushort_t s) {
    return __uint_as_float(((uint32_t)s) << 16);
}
__device__ __forceinline__ float sigm(float x) { return 1.0f / (1.0f + __expf(-x)); }
__device__ __forceinline__ float tanhx(float x) {
    float e = __expf(-2.0f * fabsf(x));
    float t = (1.0f - e) / (1.0f + e);
    return x >= 0.0f ? t : -t;
}

// ---------- cast fp32 -> bf16 (vectorized) ----------
__global__ __launch_bounds__(256) void kcast(const float* __restrict__ in,
                                             ushort_t* __restrict__ out, int n4) {
    int i = blockIdx.x * 256 + threadIdx.x;
    if (i < n4) {
        float4 v = ((const float4*)in)[i];
        ushort4 o;
        o.x = f2bf(v.x); o.y = f2bf(v.y); o.z = f2bf(v.z); o.w = f2bf(v.w);
        ((ushort4*)out)[i] = o;
    }
}

// ---------- bias fold: bias = bx + bh ----------
__global__ __launch_bounds__(256) void kbias(const float* __restrict__ bx,
                                             const float* __restrict__ bh,
                                             float* __restrict__ bias) {
    int i = blockIdx.x * 256 + threadIdx.x;
    if (i < G_) bias[i] = bx[i] + bh[i];
}

// ---------- GEMM: gx[m][n'] = sum_k xb[m][k]*wxb[n][k] + bias[n], bf16 out ----------
// Column layout swizzled for krec: logical n = gate*512 + jj*16 + d  ->  n' = jj*64 + gate*16 + d
// so each recurrence block's per-(b,t) slice is 64 contiguous values.
__global__ __launch_bounds__(256, 2) void kgemm(const ushort_t* __restrict__ A,
                                                const ushort_t* __restrict__ Bm,
                                                const float* __restrict__ bias,
                                                ushort_t* __restrict__ C) {
    __shared__ __align__(16) ushort_t LA[4096];   // [128 rows][32 k] swizzled
    __shared__ __align__(16) ushort_t LB[4096];
    const int tid = threadIdx.x;
    const int lane = tid & 63, w = tid >> 6;
    const int quad = lane >> 4, l16 = lane & 15;
    const int bn = blockIdx.x, bm = blockIdx.y;
    const int wr = w >> 1, wc = w & 1;

    f32x4 acc[4][4] = {};

    for (int kt = 0; kt < 16; ++kt) {
#pragma unroll
        for (int r = 0; r < 2; ++r) {
            int o = r * 256 + tid;           // 16B unit index
            int m = o >> 2, slot = o & 3;
            int kc = slot ^ ((m >> 1) & 3);  // stored slot = kc ^ s(m)
            const ushort_t* ga = A  + (size_t)(bm * 128 + m) * I_ + kt * 32 + kc * 8;
            const ushort_t* gb = Bm + (size_t)(bn * 128 + m) * I_ + kt * 32 + kc * 8;
            __builtin_amdgcn_global_load_lds(
                (const __attribute__((address_space(1))) void*)ga,
                (__attribute__((address_space(3))) void*)(&LA[r * 2048 + w * 512]), 16, 0, 0);
            __builtin_amdgcn_global_load_lds(
                (const __attribute__((address_space(1))) void*)gb,
                (__attribute__((address_space(3))) void*)(&LB[r * 2048 + w * 512]), 16, 0, 0);
        }
        __syncthreads();

        short8 av[4], bv[4];
#pragma unroll
        for (int mt = 0; mt < 4; ++mt) {
            int mm = wr * 64 + mt * 16 + l16;
            av[mt] = *(const short8*)&LA[mm * 32 + ((quad ^ ((mm >> 1) & 3)) << 3)];
            int nn = wc * 64 + mt * 16 + l16;
            bv[mt] = *(const short8*)&LB[nn * 32 + ((quad ^ ((nn >> 1) & 3)) << 3)];
        }
#pragma unroll
        for (int mt = 0; mt < 4; ++mt)
#pragma unroll
            for (int nt = 0; nt < 4; ++nt)
                acc[mt][nt] = __builtin_amdgcn_mfma_f32_16x16x32_bf16(av[mt], bv[nt], acc[mt][nt], 0, 0, 0);
        __syncthreads();
    }

#pragma unroll
    for (int nt = 0; nt < 4; ++nt) {
        int n = bn * 128 + wc * 64 + nt * 16 + l16;      // logical gate-space column
        int gate = n >> 9, jj = (n >> 4) & 31, d = n & 15;
        int np = jj * 64 + gate * 16 + d;                // swizzled storage column
        float bvl = bias[n];
#pragma unroll
        for (int mt = 0; mt < 4; ++mt) {
#pragma unroll
            for (int rg = 0; rg < 4; ++rg) {
                int m = bm * 128 + wr * 64 + mt * 16 + quad * 4 + rg;
                C[(size_t)m * G_ + np] = f2bf(acc[mt][nt][rg] + bvl);
            }
        }
    }
}

// ---------- recurrence ----------
// 256 blocks, 1/CU, 8 XCD-pure groups x 32 via the HW roster (hwreg(HW_REG_XCC_ID) +
// lexicographic rank + global purity AND-vote — proven rounds 8/10).
//
// ROUND-10 RESULT: L2-local exchange works (FETCH/WRITE collapsed to gx/out only).
// Remaining 2us/step = poll machinery: every failed sweep re-issued 2048 L2 requests
// per block. THIS ROUND: DONE-WORD COMPACTION + TAG-FREE DATA.
//  - data unit = 8B of 4 bf16 dims (no tag): 1024 units/parity/group, plain write-back
//    stores into the shared XCD L2.
//  - producer wave order: h-stores -> s_waitcnt vmcnt(0) (LOCAL L2 ack, ~250cy; cheap,
//    unlike round-8's fabric ack) -> lane0 stores done[j*2+wv] = n+1 (plain). Wave order
//    makes this barrier-free.
//  - consumer: poll 64 done slots (ONE atomic load/lane/sweep, 32x less L2 traffic),
//    then ONE-SHOT atomic-load its 4 data units (L1-bypass; round-9 lesson: plain/sc0
//    loads go stale in L1). Overwrite safety = same 2-step-lag invariant as the tag
//    protocol: done[j]=n+1 implies j's step-n data reads completed (data dependency
//    through the MFMA), so a producer can only overwrite parity n&1 (at end of step
//    n+1) after every block exited poll(n+1).
// Impure placement: round-2-proven tagged AGENT path verbatim (vote commits the whole
// chip to one mode). All spins capped: any failure = bounded-time wrong answer, no hang.
// Replay safety: done monotone + '>=' predicate -> instant exit on stale state.
__global__ __launch_bounds__(256, 1) void krec(const ushort_t* __restrict__ gx,
                                               const ushort_t* __restrict__ whb,
                                               unsigned long long* __restrict__ hgf,
                                               unsigned long long* __restrict__ hga,
                                               unsigned long long* __restrict__ dn,
                                               uint32_t* __restrict__ xtab,
                                               float* __restrict__ out) {
    __shared__ __align__(16) ushort_t hl[16 * 520];   // h tile, padded stride (rows 8-15 stay 0)
    __shared__ float gates[4][16][16];                // [gate][chain][dim]
    __shared__ uint32_t sx[256];
    __shared__ int s_grp, s_j, s_pure;
    const int tid = threadIdx.x;
    const int lane = tid & 63, w = tid >> 6;
    const int quad = lane >> 4, l16 = lane & 15;
    const int bk = blockIdx.x;

    // zero hl once: MFMA A-frags read all 16 rows; rows 8-15 are never written in the loop.
    for (int t = tid; t < (16 * 520) / 2; t += 256) ((uint32_t*)hl)[t] = 0;

    // ---- roster phase 1: discover XCD, publish, gather, rank ----
    uint32_t xcd;
    asm("s_getreg_b32 %0, hwreg(HW_REG_XCC_ID)" : "=s"(xcd));
    xcd &= 7u;
    if (tid == 0)
        __hip_atomic_store(&xtab[bk], 0x100u | xcd, __ATOMIC_RELAXED, __HIP_MEMORY_SCOPE_AGENT);
    {
        uint32_t e = 0;
        for (int spin = 0; spin < (1 << 16); ++spin) {   // ~20ms cap
            e = __hip_atomic_load(&xtab[tid], __ATOMIC_RELAXED, __HIP_MEMORY_SCOPE_AGENT);
            if (e & 0x100u) break;
            __builtin_amdgcn_s_sleep(8);
        }
        sx[tid] = e;
    }
    __syncthreads();
    if (tid == 0) {
        int cnt[8] = {0,0,0,0,0,0,0,0};
        int allvalid = 1;
        for (int i = 0; i < 256; ++i) {
            if (!(sx[i] & 0x100u)) allvalid = 0;
            cnt[sx[i] & 7u]++;
        }
        int balanced = allvalid;
        for (int x = 0; x < 8; ++x) if (cnt[x] != 32) balanced = 0;
        int pre[9]; pre[0] = 0;
        for (int x = 0; x < 8; ++x) pre[x + 1] = pre[x] + cnt[x];
        int rank = pre[xcd];
        for (int i = 0; i < bk; ++i) if ((sx[i] & 7u) == xcd) rank++;
        s_grp = rank >> 5; s_j = rank & 31;
        __hip_atomic_store(&xtab[256 + bk], 0x200u | (uint32_t)balanced,
                           __ATOMIC_RELAXED, __HIP_MEMORY_SCOPE_AGENT);
    }
    __syncthreads();
    // ---- roster phase 2: gather purity votes, global AND ----
    {
        uint32_t v = 0;
        for (int spin = 0; spin < (1 << 16); ++spin) {
            v = __hip_atomic_load(&xtab[256 + tid], __ATOMIC_RELAXED, __HIP_MEMORY_SCOPE_AGENT);
            if (v & 0x200u) break;
            __builtin_amdgcn_s_sleep(8);
        }
        sx[tid] = (v & 0x200u) ? (v & 1u) : 0u;   // timeout counts as impure vote
    }
    __syncthreads();
    if (tid == 0) {
        int p = 1;
        for (int i = 0; i < 256; ++i) p &= (int)sx[i];
        s_pure = p;
    }
    __syncthreads();
    const int grp = s_grp, j = s_j;
    const bool pure = (s_pure != 0);

    // Wh B-frags for this wave's gate section, cols j*16..+16 (rows of Wh = gate outputs)
    short8 bw[16];
    {
        const ushort_t* wp = whb + (size_t)(w * H_ + j * 16 + l16) * H_ + quad * 8;
#pragma unroll
        for (int kc = 0; kc < 16; ++kc) bw[kc] = *(const short8*)(wp + kc * 32);
    }

    const int r = tid >> 4, d = tid & 15;     // consumer role: r in 0..15, d in 0..15
    const int rr = r & 7, half = r >> 3;      // chain, coverage-half
    const bool cell = (tid < 128);            // cell-update threads: chain r (0..7), dim d
    const int b = grp * 4 + (r & 3), dir = (r >> 2) & 1;
    const int wv = (r >> 2) & 1 ? 0 : 0;      // (placeholder, see below)
    const int cwave = tid >> 6;               // 0..3; cell waves are 0 and 1
    float c = 0.0f;                           // cell state in register

    unsigned long long* hgrpF = hgf + (size_t)grp * 2048;   // fast: 2 par x 1024 tag-free units
    unsigned long long* hgrpA = hga + (size_t)grp * 4096;   // agent path: 2 par x 2048 tagged
    unsigned long long* dgrp  = dn  + (size_t)grp * 64;     // 64 done slots (j*2 + cellwave)

    // pure consumer: 4 data units at rr*128 + half*64 + d*4 + {0..3} (32B contiguous)
    const int fbase = rr * 128 + half * 64 + d * 4;
    // impure consumer: 8 tagged units at rr*256 + half*128 + d*4 (+64)
    const int abase = rr * 256 + half * 128 + d * 4;

    for (int n = 0; n < 512; ++n) {
        // ---- prefetch gx for this step (independent of h, overlaps the poll) ----
        ushort_t g0 = 0, g1 = 0, g2 = 0, g3 = 0;
        if (cell) {
            int te = dir ? (511 - n) : n;
            const ushort_t* gp = gx + (size_t)(b * T_ + te) * G_ + j * 64 + d;
            g0 = gp[0]; g1 = gp[16]; g2 = gp[32]; g3 = gp[48];
        }

        const uint32_t un = (uint32_t)n;

        if (pure) {
            // ---- done poll: 1 atomic load/lane/sweep over 64 slots ----
            for (int spin = 0; spin < 8192; ++spin) {
                unsigned long long v = __hip_atomic_load(dgrp + lane, __ATOMIC_RELAXED,
                                                         __HIP_MEMORY_SCOPE_AGENT);
                if (__all((uint32_t)v >= un)) break;
                __builtin_amdgcn_s_sleep(1);
            }
            // ---- one-shot data load: 4 atomic 8B loads (L1-bypass), 32B contiguous ----
            const unsigned long long* f0 = hgrpF + (size_t)(n & 1) * 1024 + fbase;
            unsigned long long t0 = __hip_atomic_load(f0 + 0, __ATOMIC_RELAXED, __HIP_MEMORY_SCOPE_AGENT);
            unsigned long long t1 = __hip_atomic_load(f0 + 1, __ATOMIC_RELAXED, __HIP_MEMORY_SCOPE_AGENT);
            unsigned long long t2 = __hip_atomic_load(f0 + 2, __ATOMIC_RELAXED, __HIP_MEMORY_SCOPE_AGENT);
            unsigned long long t3 = __hip_atomic_load(f0 + 3, __ATOMIC_RELAXED, __HIP_MEMORY_SCOPE_AGENT);
            // ---- unpack 16 dims to LDS: 2x ds_write_b128 ----
            uint4 p0, p1;
            p0.x = (uint32_t)t0; p0.y = (uint32_t)(t0 >> 32);
            p0.z = (uint32_t)t1; p0.w = (uint32_t)(t1 >> 32);
            p1.x = (uint32_t)t2; p1.y = (uint32_t)(t2 >> 32);
            p1.z = (uint32_t)t3; p1.w = (uint32_t)(t3 >> 32);
            int hb = rr * 520 + half * 256 + d * 16;
            *(uint4*)&hl[hb] = p0;
            *(uint4*)&hl[hb + 8] = p1;
        } else {
            // ---- AGENT path (round-2/5-proven), tagged units, sleep-throttled ----
            const unsigned long long* a0 = hgrpA + (size_t)(n & 1) * 2048 + abase;
            unsigned long long tv[8];
            for (int spin = 0; spin < 600; ++spin) {
#pragma unroll
                for (int i = 0; i < 8; ++i)
                    tv[i] = __hip_atomic_load(a0 + (i >> 2) * 64 + (i & 3),
                                              __ATOMIC_RELAXED, __HIP_MEMORY_SCOPE_AGENT);
                bool ok = true;
#pragma unroll
                for (int i = 0; i < 8; ++i)
                    ok &= ((uint32_t)(tv[i] >> 32) >= un);
                if (ok) break;
                __builtin_amdgcn_s_sleep(4);
            }
#pragma unroll
            for (int cc = 0; cc < 2; ++cc) {
                uint4 pk;
                pk.x = (uint32_t)tv[cc * 4 + 0];
                pk.y = (uint32_t)tv[cc * 4 + 1];
                pk.z = (uint32_t)tv[cc * 4 + 2];
                pk.w = (uint32_t)tv[cc * 4 + 3];
                *(uint4*)&hl[rr * 520 + half * 256 + cc * 128 + d * 8] = pk;
            }
        }
        __syncthreads();

        // ---- gates = h @ Wh_section^T (two independent MFMA chains) ----
        f32x4 acc0 = {}, acc1 = {};
#pragma unroll
        for (int kc = 0; kc < 16; kc += 2) {
            short8 av0 = *(const short8*)&hl[l16 * 520 + kc * 32 + quad * 8];
            acc0 = __builtin_amdgcn_mfma_f32_16x16x32_bf16(av0, bw[kc], acc0, 0, 0, 0);
            short8 av1 = *(const short8*)&hl[l16 * 520 + (kc + 1) * 32 + quad * 8];
            acc1 = __builtin_amdgcn_mfma_f32_16x16x32_bf16(av1, bw[kc + 1], acc1, 0, 0, 0);
        }
        f32x4 acc = acc0 + acc1;
#pragma unroll
        for (int rg = 0; rg < 4; ++rg) gates[w][quad * 4 + rg][l16] = acc[rg];
        __syncthreads();

        // ---- cell update: thread -> (chain r, dim d), chains 0..7 only ----
        if (cell) {
            float gi = gates[0][r][d] + bf2f(g0);
            float gf = gates[1][r][d] + bf2f(g1);
            float gg = gates[2][r][d] + bf2f(g2);
            float go = gates[3][r][d] + bf2f(g3);
            float it = sigm(gi), ft = sigm(gf), gt = tanhx(gg), ot = sigm(go);
            c = c * ft + it * gt;
            float h = ot * tanhx(c);

            int hv = (int)f2bf(h);
            if (pure) {
                // ---- tag-free publish: 4 dims/unit, then wave-ordered done signal ----
                int v1 = __shfl(hv, lane + 1);
                int v2 = __shfl(hv, lane + 2);
                int v3 = __shfl(hv, lane + 3);
                if (!(d & 3)) {
                    uint2 uv;
                    uv.x = ((uint32_t)hv & 0xFFFFu) | ((uint32_t)v1 << 16);
                    uv.y = ((uint32_t)v2 & 0xFFFFu) | ((uint32_t)v3 << 16);
                    unsigned long long* fp = hgrpF + (size_t)((n + 1) & 1) * 1024
                                           + (size_t)r * 128 + j * 4 + (d >> 2);
                    asm volatile("global_store_dwordx2 %0, %1, off"
                                 :: "v"((void*)fp), "v"(uv) : "memory");
                }
                asm volatile("s_waitcnt vmcnt(0)");   // local-L2 acks only (cheap)
                if (lane == 0) {
                    uint2 dv; dv.x = (uint32_t)(n + 1); dv.y = 0;
                    unsigned long long* dp = dgrp + (size_t)j * 2 + cwave;
                    asm volatile("global_store_dwordx2 %0, %1, off"
                                 :: "v"((void*)dp), "v"(dv) : "memory");
                }
            } else {
                // ---- tagged agent publish (fabric) ----
                int vo = __shfl(hv, lane ^ 1);
                if (!(d & 1)) {
                    uint32_t payv = (((uint32_t)vo & 0xFFFFu) << 16) | ((uint32_t)hv & 0xFFFFu);
                    unsigned long long unit =
                        ((unsigned long long)(uint32_t)(n + 1) << 32) | payv;
                    size_t u = (size_t)((n + 1) & 1) * 2048 + (size_t)r * 256 + j * 8 + (d >> 1);
                    __hip_atomic_store(hgrpA + u, unit,
                                       __ATOMIC_RELAXED, __HIP_MEMORY_SCOPE_AGENT);
                }
            }
            out[(size_t)b * (T_ * 2 * H_) + (size_t)n * (2 * H_) + dir * H_ + j * 16 + d] = h;
        }
    }
}

// ---------- workspace layout (bytes) ----------
// HGF/HGA/DONE/XTAB alias XB: xb is dead after kgemm; memset issued after kgemm in-stream.
#define GX_OFF    ((size_t)0)                    // 16384*2048*2 = 67108864
#define XB_OFF    ((size_t)67108864)             // 16384*512*2 = 16777216
#define HGF_OFF   XB_OFF                         // 8 grp * 2 par * 1024 units * 8B = 131072
#define HGA_OFF   (XB_OFF + 131072)              // 8 grp * 2 par * 2048 units * 8B = 262144
#define DONE_OFF  (XB_OFF + 393216)              // 8 grp * 64 slots * 8B = 4096
#define XTAB_OFF  (XB_OFF + 397312)              // 512 * 4 = 2048
#define HG_BYTES  ((size_t)(397312 + 2048))
#define WXB_OFF   ((size_t)83886080)             // 2048*512*2  = 2097152
#define WHB_OFF   ((size_t)85983232)             // 2048*512*2  = 2097152
#define BIAS_OFF  ((size_t)88080384)             // 2048*4      = 8192
#define WS_NEED   ((size_t)88088576)

extern "C" void kernel_launch(void* const* d_in, const int* in_sizes, int n_in,
                              void* d_out, int out_size, void* d_ws, size_t ws_size,
                              hipStream_t stream) {
    if (ws_size < WS_NEED) return;

    const float* x  = (const float*)d_in[0];
    const float* Wx = (const float*)d_in[1];
    const float* bx = (const float*)d_in[2];
    const float* Wh = (const float*)d_in[3];
    const float* bh = (const float*)d_in[4];
    float* out = (float*)d_out;
    char* ws = (char*)d_ws;

    ushort_t* gx   = (ushort_t*)(ws + GX_OFF);
    ushort_t* xb   = (ushort_t*)(ws + XB_OFF);
    ushort_t* wxb  = (ushort_t*)(ws + WXB_OFF);
    ushort_t* whb  = (ushort_t*)(ws + WHB_OFF);
    float*    bias = (float*)(ws + BIAS_OFF);
    unsigned long long* hgf = (unsigned long long*)(ws + HGF_OFF);
    unsigned long long* hga = (unsigned long long*)(ws + HGA_OFF);
    unsigned long long* dn  = (unsigned long long*)(ws + DONE_OFF);
    uint32_t* xtab = (uint32_t*)(ws + XTAB_OFF);

    // casts
    kcast<<<dim3((B_ * T_ * I_ / 4 + 255) / 256), 256, 0, stream>>>(x, xb, B_ * T_ * I_ / 4);
    kcast<<<dim3((G_ * I_ / 4 + 255) / 256), 256, 0, stream>>>(Wx, wxb, G_ * I_ / 4);
    kcast<<<dim3((G_ * H_ / 4 + 255) / 256), 256, 0, stream>>>(Wh, whb, G_ * H_ / 4);
    kbias<<<dim3(G_ / 256), 256, 0, stream>>>(bx, bh, bias);

    // input projection GEMM: grid (N/128, M/128) = (16, 128)
    kgemm<<<dim3(G_ / 128, (B_ * T_) / 128), 256, 0, stream>>>(xb, wxb, bias, gx);

    // zero fast/agent h buffers + done slots + roster/vote table.
    // memset-0 == valid step-0 state (h0 = 0, done = 0 >= 0, tags = 0).
    // Must run after kgemm: they alias the then-dead xb region.
    hipMemsetAsync(ws + HGF_OFF, 0, HG_BYTES, stream);

    // recurrence: 256 persistent blocks (8 XCD-pure groups x 32), one per CU
    krec<<<dim3(256), 256, 0, stream>>>(gx, whb, hgf, hga, dn, xtab, out);
}

// Round 12
// 938.345 us; speedup vs baseline: 4.6857x; 1.0171x over previous
//
#include <hip/hip_runtime.h>
#include <stdint.h>

typedef unsigned short ushort_t;
typedef float f32x4 __attribute__((ext_vector_type(4)));
typedef short short8 __attribute__((ext_vector_type(8)));

#define B_ 32
#define T_ 512
#define I_ 512
#define H_ 512
#define G_ 2048   // 4*H

// ---------- helpers ----------
__device__ __forceinline__ ushort_t f2bf(float f) {
    uint32_t u = __float_as_uint(f);
    u += 0x7FFFu + ((u >> 16) & 1u);   // RNE
    return (ushort_t)(u >> 16);
}
__device__ __forceinline__ float bf2f(ushort_t s) {
    return __uint_as_float(((uint32_t)s) << 16);
}
__device__ __forceinline__ float sigm(float x) { return 1.0f / (1.0f + __expf(-x)); }
__device__ __forceinline__ float tanhx(float x) {
    float e = __expf(-2.0f * fabsf(x));
    float t = (1.0f - e) / (1.0f + e);
    return x >= 0.0f ? t : -t;
}

// ---------- cast fp32 -> bf16 (vectorized) ----------
__global__ __launch_bounds__(256) void kcast(const float* __restrict__ in,
                                             ushort_t* __restrict__ out, int n4) {
    int i = blockIdx.x * 256 + threadIdx.x;
    if (i < n4) {
        float4 v = ((const float4*)in)[i];
        ushort4 o;
        o.x = f2bf(v.x); o.y = f2bf(v.y); o.z = f2bf(v.z); o.w = f2bf(v.w);
        ((ushort4*)out)[i] = o;
    }
}

// ---------- bias fold: bias = bx + bh ----------
__global__ __launch_bounds__(256) void kbias(const float* __restrict__ bx,
                                             const float* __restrict__ bh,
                                             float* __restrict__ bias) {
    int i = blockIdx.x * 256 + threadIdx.x;
    if (i < G_) bias[i] = bx[i] + bh[i];
}

// ---------- GEMM: gx[m][n'] = sum_k xb[m][k]*wxb[n][k] + bias[n], bf16 out ----------
// Column layout swizzled for krec: logical n = gate*512 + jj*16 + d  ->  n' = jj*64 + gate*16 + d
// so each recurrence block's per-(b,t) slice is 64 contiguous values.
__global__ __launch_bounds__(256, 2) void kgemm(const ushort_t* __restrict__ A,
                                                const ushort_t* __restrict__ Bm,
                                                const float* __restrict__ bias,
                                                ushort_t* __restrict__ C) {
    __shared__ __align__(16) ushort_t LA[4096];   // [128 rows][32 k] swizzled
    __shared__ __align__(16) ushort_t LB[4096];
    const int tid = threadIdx.x;
    const int lane = tid & 63, w = tid >> 6;
    const int quad = lane >> 4, l16 = lane & 15;
    const int bn = blockIdx.x, bm = blockIdx.y;
    const int wr = w >> 1, wc = w & 1;

    f32x4 acc[4][4] = {};

    for (int kt = 0; kt < 16; ++kt) {
#pragma unroll
        for (int r = 0; r < 2; ++r) {
            int o = r * 256 + tid;           // 16B unit index
            int m = o >> 2, slot = o & 3;
            int kc = slot ^ ((m >> 1) & 3);  // stored slot = kc ^ s(m)
            const ushort_t* ga = A  + (size_t)(bm * 128 + m) * I_ + kt * 32 + kc * 8;
            const ushort_t* gb = Bm + (size_t)(bn * 128 + m) * I_ + kt * 32 + kc * 8;
            __builtin_amdgcn_global_load_lds(
                (const __attribute__((address_space(1))) void*)ga,
                (__attribute__((address_space(3))) void*)(&LA[r * 2048 + w * 512]), 16, 0, 0);
            __builtin_amdgcn_global_load_lds(
                (const __attribute__((address_space(1))) void*)gb,
                (__attribute__((address_space(3))) void*)(&LB[r * 2048 + w * 512]), 16, 0, 0);
        }
        __syncthreads();

        short8 av[4], bv[4];
#pragma unroll
        for (int mt = 0; mt < 4; ++mt) {
            int mm = wr * 64 + mt * 16 + l16;
            av[mt] = *(const short8*)&LA[mm * 32 + ((quad ^ ((mm >> 1) & 3)) << 3)];
            int nn = wc * 64 + mt * 16 + l16;
            bv[mt] = *(const short8*)&LB[nn * 32 + ((quad ^ ((nn >> 1) & 3)) << 3)];
        }
#pragma unroll
        for (int mt = 0; mt < 4; ++mt)
#pragma unroll
            for (int nt = 0; nt < 4; ++nt)
                acc[mt][nt] = __builtin_amdgcn_mfma_f32_16x16x32_bf16(av[mt], bv[nt], acc[mt][nt], 0, 0, 0);
        __syncthreads();
    }

#pragma unroll
    for (int nt = 0; nt < 4; ++nt) {
        int n = bn * 128 + wc * 64 + nt * 16 + l16;      // logical gate-space column
        int gate = n >> 9, jj = (n >> 4) & 31, d = n & 15;
        int np = jj * 64 + gate * 16 + d;                // swizzled storage column
        float bvl = bias[n];
#pragma unroll
        for (int mt = 0; mt < 4; ++mt) {
#pragma unroll
            for (int rg = 0; rg < 4; ++rg) {
                int m = bm * 128 + wr * 64 + mt * 16 + quad * 4 + rg;
                C[(size_t)m * G_ + np] = f2bf(acc[mt][nt][rg] + bvl);
            }
        }
    }
}

// ---------- recurrence ----------
// 256 blocks, 1/CU, 8 XCD-pure groups x 32 via the HW roster (hwreg(HW_REG_XCC_ID) +
// lexicographic rank + global purity AND-vote — proven rounds 8/10/11).
//
// ROUND-11 RESULT: done-word compaction -> 828us. Remaining ~3000cy/step over compute:
// ALL 32 blocks x 4 waves polled the SAME 64 done slots = 8 L2 lines shared by 32 CUs
// (~2048 concurrent atomics on 8 hot lines per sweep -> ~250cy/sweep serialization), plus
// s_sleep(1) quantization. THIS ROUND: PRIVATE DONE COPIES.
//  - producer cell waves, after local-L2 vmcnt(0) ack, lanes 0..31 store done=n+1 into
//    32 per-consumer copies (512B apart, one 8B store/lane, one line per consumer).
//  - each consumer polls ONLY its own 64-slot region (8 private lines, no cross-CU
//    sharing), no sleep. Sharpened mapping: thread (rr,half,d) polls exactly its
//    producer's slot (block jp=half*16+d, cellwave rr>>2); wave exits on __all;
//    __syncthreads preserves the global all-producers guarantee.
// Overwrite safety (2-step lag) carries over: a producer stores a consumer's done copy
// only after its own reads of the old parity completed (program order through MFMA),
// so done[*]>=n at poll(n) implies all reads of parity (n-1)&1 are done before it is
// overwritten at end of step n. Data unit = 8B of 4 bf16 dims (tag-free), plain
// write-back stores; consumer one-shot atomic loads (L1-bypass — round-9 lesson).
// Impure placement: round-2-proven tagged AGENT path verbatim. All spins capped:
// any failure = bounded-time wrong answer, no hang. Replay-safe: done monotone + '>='.
__global__ __launch_bounds__(256, 1) void krec(const ushort_t* __restrict__ gx,
                                               const ushort_t* __restrict__ whb,
                                               unsigned long long* __restrict__ hgf,
                                               unsigned long long* __restrict__ hga,
                                               unsigned long long* __restrict__ dn,
                                               uint32_t* __restrict__ xtab,
                                               float* __restrict__ out) {
    __shared__ __align__(16) ushort_t hl[16 * 520];   // h tile, padded stride (rows 8-15 stay 0)
    __shared__ float gates[4][16][16];                // [gate][chain][dim]
    __shared__ uint32_t sx[256];
    __shared__ int s_grp, s_j, s_pure;
    const int tid = threadIdx.x;
    const int lane = tid & 63, w = tid >> 6;
    const int quad = lane >> 4, l16 = lane & 15;
    const int bk = blockIdx.x;

    // zero hl once: MFMA A-frags read all 16 rows; rows 8-15 are never written in the loop.
    for (int t = tid; t < (16 * 520) / 2; t += 256) ((uint32_t*)hl)[t] = 0;

    // ---- roster phase 1: discover XCD, publish, gather, rank ----
    uint32_t xcd;
    asm("s_getreg_b32 %0, hwreg(HW_REG_XCC_ID)" : "=s"(xcd));
    xcd &= 7u;
    if (tid == 0)
        __hip_atomic_store(&xtab[bk], 0x100u | xcd, __ATOMIC_RELAXED, __HIP_MEMORY_SCOPE_AGENT);
    {
        uint32_t e = 0;
        for (int spin = 0; spin < (1 << 16); ++spin) {   // ~20ms cap
            e = __hip_atomic_load(&xtab[tid], __ATOMIC_RELAXED, __HIP_MEMORY_SCOPE_AGENT);
            if (e & 0x100u) break;
            __builtin_amdgcn_s_sleep(8);
        }
        sx[tid] = e;
    }
    __syncthreads();
    if (tid == 0) {
        int cnt[8] = {0,0,0,0,0,0,0,0};
        int allvalid = 1;
        for (int i = 0; i < 256; ++i) {
            if (!(sx[i] & 0x100u)) allvalid = 0;
            cnt[sx[i] & 7u]++;
        }
        int balanced = allvalid;
        for (int x = 0; x < 8; ++x) if (cnt[x] != 32) balanced = 0;
        int pre[9]; pre[0] = 0;
        for (int x = 0; x < 8; ++x) pre[x + 1] = pre[x] + cnt[x];
        int rank = pre[xcd];
        for (int i = 0; i < bk; ++i) if ((sx[i] & 7u) == xcd) rank++;
        s_grp = rank >> 5; s_j = rank & 31;
        __hip_atomic_store(&xtab[256 + bk], 0x200u | (uint32_t)balanced,
                           __ATOMIC_RELAXED, __HIP_MEMORY_SCOPE_AGENT);
    }
    __syncthreads();
    // ---- roster phase 2: gather purity votes, global AND ----
    {
        uint32_t v = 0;
        for (int spin = 0; spin < (1 << 16); ++spin) {
            v = __hip_atomic_load(&xtab[256 + tid], __ATOMIC_RELAXED, __HIP_MEMORY_SCOPE_AGENT);
            if (v & 0x200u) break;
            __builtin_amdgcn_s_sleep(8);
        }
        sx[tid] = (v & 0x200u) ? (v & 1u) : 0u;   // timeout counts as impure vote
    }
    __syncthreads();
    if (tid == 0) {
        int p = 1;
        for (int i = 0; i < 256; ++i) p &= (int)sx[i];
        s_pure = p;
    }
    __syncthreads();
    const int grp = s_grp, j = s_j;
    const bool pure = (s_pure != 0);

    // Wh B-frags for this wave's gate section, cols j*16..+16 (rows of Wh = gate outputs)
    short8 bw[16];
    {
        const ushort_t* wp = whb + (size_t)(w * H_ + j * 16 + l16) * H_ + quad * 8;
#pragma unroll
        for (int kc = 0; kc < 16; ++kc) bw[kc] = *(const short8*)(wp + kc * 32);
    }

    const int r = tid >> 4, d = tid & 15;     // consumer role: r in 0..15, d in 0..15
    const int rr = r & 7, half = r >> 3;      // chain, coverage-half
    const bool cell = (tid < 128);            // cell-update threads: chain r (0..7), dim d
    const int b = grp * 4 + (r & 3), dir = (r >> 2) & 1;
    const int cwave = tid >> 6;               // cell waves are 0 and 1
    float c = 0.0f;                           // cell state in register

    unsigned long long* hgrpF = hgf + (size_t)grp * 2048;   // fast: 2 par x 1024 tag-free units
    unsigned long long* hgrpA = hga + (size_t)grp * 4096;   // agent path: 2 par x 2048 tagged
    unsigned long long* dgrp  = dn  + (size_t)grp * 2048;   // 32 consumer copies x 64 slots

    // pure consumer: 4 data units at rr*128 + half*64 + d*4 + {0..3} (32B, one line),
    // produced by block jp = half*16+d, cell wave rr>>2. Private done slot:
    const int myslot = (half * 16 + d) * 2 + (rr >> 2);
    const unsigned long long* mydone = dgrp + (size_t)j * 64 + myslot;
    const int fbase = rr * 128 + half * 64 + d * 4;
    // impure consumer: 8 tagged units at rr*256 + half*128 + d*4 (+64)
    const int abase = rr * 256 + half * 128 + d * 4;

    for (int n = 0; n < 512; ++n) {
        // ---- prefetch gx for this step (independent of h, overlaps the poll) ----
        ushort_t g0 = 0, g1 = 0, g2 = 0, g3 = 0;
        if (cell) {
            int te = dir ? (511 - n) : n;
            const ushort_t* gp = gx + (size_t)(b * T_ + te) * G_ + j * 64 + d;
            g0 = gp[0]; g1 = gp[16]; g2 = gp[32]; g3 = gp[48];
        }

        const uint32_t un = (uint32_t)n;

        if (pure) {
            // ---- private done poll: 1 atomic load/lane/sweep, own 8-line region ----
            for (int spin = 0; spin < 4096; ++spin) {
                unsigned long long v = __hip_atomic_load(mydone, __ATOMIC_RELAXED,
                                                         __HIP_MEMORY_SCOPE_AGENT);
                if (__all((uint32_t)v >= un)) break;
            }
            // ---- one-shot data load: 4 atomic 8B loads (L1-bypass), one 64B line ----
            const unsigned long long* f0 = hgrpF + (size_t)(n & 1) * 1024 + fbase;
            unsigned long long t0 = __hip_atomic_load(f0 + 0, __ATOMIC_RELAXED, __HIP_MEMORY_SCOPE_AGENT);
            unsigned long long t1 = __hip_atomic_load(f0 + 1, __ATOMIC_RELAXED, __HIP_MEMORY_SCOPE_AGENT);
            unsigned long long t2 = __hip_atomic_load(f0 + 2, __ATOMIC_RELAXED, __HIP_MEMORY_SCOPE_AGENT);
            unsigned long long t3 = __hip_atomic_load(f0 + 3, __ATOMIC_RELAXED, __HIP_MEMORY_SCOPE_AGENT);
            // ---- unpack 16 dims to LDS: 2x ds_write_b128 ----
            uint4 p0, p1;
            p0.x = (uint32_t)t0; p0.y = (uint32_t)(t0 >> 32);
            p0.z = (uint32_t)t1; p0.w = (uint32_t)(t1 >> 32);
            p1.x = (uint32_t)t2; p1.y = (uint32_t)(t2 >> 32);
            p1.z = (uint32_t)t3; p1.w = (uint32_t)(t3 >> 32);
            int hb = rr * 520 + half * 256 + d * 16;
            *(uint4*)&hl[hb] = p0;
            *(uint4*)&hl[hb + 8] = p1;
        } else {
            // ---- AGENT path (round-2/5-proven), tagged units, sleep-throttled ----
            const unsigned long long* a0 = hgrpA + (size_t)(n & 1) * 2048 + abase;
            unsigned long long tv[8];
            for (int spin = 0; spin < 600; ++spin) {
#pragma unroll
                for (int i = 0; i < 8; ++i)
                    tv[i] = __hip_atomic_load(a0 + (i >> 2) * 64 + (i & 3),
                                              __ATOMIC_RELAXED, __HIP_MEMORY_SCOPE_AGENT);
                bool ok = true;
#pragma unroll
                for (int i = 0; i < 8; ++i)
                    ok &= ((uint32_t)(tv[i] >> 32) >= un);
                if (ok) break;
                __builtin_amdgcn_s_sleep(4);
            }
#pragma unroll
            for (int cc = 0; cc < 2; ++cc) {
                uint4 pk;
                pk.x = (uint32_t)tv[cc * 4 + 0];
                pk.y = (uint32_t)tv[cc * 4 + 1];
                pk.z = (uint32_t)tv[cc * 4 + 2];
                pk.w = (uint32_t)tv[cc * 4 + 3];
                *(uint4*)&hl[rr * 520 + half * 256 + cc * 128 + d * 8] = pk;
            }
        }
        __syncthreads();

        // ---- gates = h @ Wh_section^T (two independent MFMA chains) ----
        f32x4 acc0 = {}, acc1 = {};
#pragma unroll
        for (int kc = 0; kc < 16; kc += 2) {
            short8 av0 = *(const short8*)&hl[l16 * 520 + kc * 32 + quad * 8];
            acc0 = __builtin_amdgcn_mfma_f32_16x16x32_bf16(av0, bw[kc], acc0, 0, 0, 0);
            short8 av1 = *(const short8*)&hl[l16 * 520 + (kc + 1) * 32 + quad * 8];
            acc1 = __builtin_amdgcn_mfma_f32_16x16x32_bf16(av1, bw[kc + 1], acc1, 0, 0, 0);
        }
        f32x4 acc = acc0 + acc1;
#pragma unroll
        for (int rg = 0; rg < 4; ++rg) gates[w][quad * 4 + rg][l16] = acc[rg];
        __syncthreads();

        // ---- cell update: thread -> (chain r, dim d), chains 0..7 only ----
        if (cell) {
            float gi = gates[0][r][d] + bf2f(g0);
            float gf = gates[1][r][d] + bf2f(g1);
            float gg = gates[2][r][d] + bf2f(g2);
            float go = gates[3][r][d] + bf2f(g3);
            float it = sigm(gi), ft = sigm(gf), gt = tanhx(gg), ot = sigm(go);
            c = c * ft + it * gt;
            float h = ot * tanhx(c);

            int hv = (int)f2bf(h);
            if (pure) {
                // ---- tag-free publish: 4 dims/unit, ack, then 32 private done copies ----
                int v1 = __shfl(hv, lane + 1);
                int v2 = __shfl(hv, lane + 2);
                int v3 = __shfl(hv, lane + 3);
                if (!(d & 3)) {
                    uint2 uv;
                    uv.x = ((uint32_t)hv & 0xFFFFu) | ((uint32_t)v1 << 16);
                    uv.y = ((uint32_t)v2 & 0xFFFFu) | ((uint32_t)v3 << 16);
                    unsigned long long* fp = hgrpF + (size_t)((n + 1) & 1) * 1024
                                           + (size_t)r * 128 + j * 4 + (d >> 2);
                    asm volatile("global_store_dwordx2 %0, %1, off"
                                 :: "v"((void*)fp), "v"(uv) : "memory");
                }
                asm volatile("s_waitcnt vmcnt(0)");   // local-L2 acks only (cheap)
                if (lane < 32) {
                    uint2 dv; dv.x = (uint32_t)(n + 1); dv.y = 0;
                    unsigned long long* dp = dgrp + (size_t)lane * 64 + (size_t)j * 2 + cwave;
                    asm volatile("global_store_dwordx2 %0, %1, off"
                                 :: "v"((void*)dp), "v"(dv) : "memory");
                }
            } else {
                // ---- tagged agent publish (fabric) ----
                int vo = __shfl(hv, lane ^ 1);
                if (!(d & 1)) {
                    uint32_t payv = (((uint32_t)vo & 0xFFFFu) << 16) | ((uint32_t)hv & 0xFFFFu);
                    unsigned long long unit =
                        ((unsigned long long)(uint32_t)(n + 1) << 32) | payv;
                    size_t u = (size_t)((n + 1) & 1) * 2048 + (size_t)r * 256 + j * 8 + (d >> 1);
                    __hip_atomic_store(hgrpA + u, unit,
                                       __ATOMIC_RELAXED, __HIP_MEMORY_SCOPE_AGENT);
                }
            }
            out[(size_t)b * (T_ * 2 * H_) + (size_t)n * (2 * H_) + dir * H_ + j * 16 + d] = h;
        }
    }
}

// ---------- workspace layout (bytes) ----------
// HGF/HGA/DONE/XTAB alias XB: xb is dead after kgemm; memset issued after kgemm in-stream.
#define GX_OFF    ((size_t)0)                    // 16384*2048*2 = 67108864
#define XB_OFF    ((size_t)67108864)             // 16384*512*2 = 16777216
#define HGF_OFF   XB_OFF                         // 8 grp * 2 par * 1024 units * 8B = 131072
#define HGA_OFF   (XB_OFF + 131072)              // 8 grp * 2 par * 2048 units * 8B = 262144
#define DONE_OFF  (XB_OFF + 393216)              // 8 grp * 32 copies * 64 slots * 8B = 131072
#define XTAB_OFF  (XB_OFF + 524288)              // 512 * 4 = 2048
#define HG_BYTES  ((size_t)(524288 + 2048))
#define WXB_OFF   ((size_t)83886080)             // 2048*512*2  = 2097152
#define WHB_OFF   ((size_t)85983232)             // 2048*512*2  = 2097152
#define BIAS_OFF  ((size_t)88080384)             // 2048*4      = 8192
#define WS_NEED   ((size_t)88088576)

extern "C" void kernel_launch(void* const* d_in, const int* in_sizes, int n_in,
                              void* d_out, int out_size, void* d_ws, size_t ws_size,
                              hipStream_t stream) {
    if (ws_size < WS_NEED) return;

    const float* x  = (const float*)d_in[0];
    const float* Wx = (const float*)d_in[1];
    const float* bx = (const float*)d_in[2];
    const float* Wh = (const float*)d_in[3];
    const float* bh = (const float*)d_in[4];
    float* out = (float*)d_out;
    char* ws = (char*)d_ws;

    ushort_t* gx   = (ushort_t*)(ws + GX_OFF);
    ushort_t* xb   = (ushort_t*)(ws + XB_OFF);
    ushort_t* wxb  = (ushort_t*)(ws + WXB_OFF);
    ushort_t* whb  = (ushort_t*)(ws + WHB_OFF);
    float*    bias = (float*)(ws + BIAS_OFF);
    unsigned long long* hgf = (unsigned long long*)(ws + HGF_OFF);
    unsigned long long* hga = (unsigned long long*)(ws + HGA_OFF);
    unsigned long long* dn  = (unsigned long long*)(ws + DONE_OFF);
    uint32_t* xtab = (uint32_t*)(ws + XTAB_OFF);

    // casts
    kcast<<<dim3((B_ * T_ * I_ / 4 + 255) / 256), 256, 0, stream>>>(x, xb, B_ * T_ * I_ / 4);
    kcast<<<dim3((G_ * I_ / 4 + 255) / 256), 256, 0, stream>>>(Wx, wxb, G_ * I_ / 4);
    kcast<<<dim3((G_ * H_ / 4 + 255) / 256), 256, 0, stream>>>(Wh, whb, G_ * H_ / 4);
    kbias<<<dim3(G_ / 256), 256, 0, stream>>>(bx, bh, bias);

    // input projection GEMM: grid (N/128, M/128) = (16, 128)
    kgemm<<<dim3(G_ / 128, (B_ * T_) / 128), 256, 0, stream>>>(xb, wxb, bias, gx);

    // zero fast/agent h buffers + private done copies + roster/vote table.
    // memset-0 == valid step-0 state (h0 = 0, done = 0 >= 0, tags = 0).
    // Must run after kgemm: they alias the then-dead xb region.
    hipMemsetAsync(ws + HGF_OFF, 0, HG_BYTES, stream);

    // recurrence: 256 persistent blocks (8 XCD-pure groups x 32), one per CU
    krec<<<dim3(256), 256, 0, stream>>>(gx, whb, hgf, hga, dn, xtab, out);
}

// Round 13
// 934.626 us; speedup vs baseline: 4.7043x; 1.0040x over previous
//
#include <hip/hip_runtime.h>
#include <stdint.h>

typedef unsigned short ushort_t;
typedef float f32x4 __attribute__((ext_vector_type(4)));
typedef short short8 __attribute__((ext_vector_type(8)));

#define B_ 32
#define T_ 512
#define I_ 512
#define H_ 512
#define G_ 2048   // 4*H

// ---------- helpers ----------
__device__ __forceinline__ ushort_t f2bf(float f) {
    uint32_t u = __float_as_uint(f);
    u += 0x7FFFu + ((u >> 16) & 1u);   // RNE
    return (ushort_t)(u >> 16);
}
__device__ __forceinline__ float bf2f(ushort_t s) {
    return __uint_as_float(((uint32_t)s) << 16);
}
__device__ __forceinline__ float sigm(float x) { return 1.0f / (1.0f + __expf(-x)); }
__device__ __forceinline__ float tanhx(float x) {
    float e = __expf(-2.0f * fabsf(x));
    float t = (1.0f - e) / (1.0f + e);
    return x >= 0.0f ? t : -t;
}

// ---------- cast fp32 -> bf16 (vectorized) ----------
__global__ __launch_bounds__(256) void kcast(const float* __restrict__ in,
                                             ushort_t* __restrict__ out, int n4) {
    int i = blockIdx.x * 256 + threadIdx.x;
    if (i < n4) {
        float4 v = ((const float4*)in)[i];
        ushort4 o;
        o.x = f2bf(v.x); o.y = f2bf(v.y); o.z = f2bf(v.z); o.w = f2bf(v.w);
        ((ushort4*)out)[i] = o;
    }
}

// ---------- bias fold: bias = bx + bh ----------
__global__ __launch_bounds__(256) void kbias(const float* __restrict__ bx,
                                             const float* __restrict__ bh,
                                             float* __restrict__ bias) {
    int i = blockIdx.x * 256 + threadIdx.x;
    if (i < G_) bias[i] = bx[i] + bh[i];
}

// ---------- GEMM: gx[m][n'] = sum_k xb[m][k]*wxb[n][k] + bias[n], bf16 out ----------
// Column layout swizzled for krec: logical n = gate*512 + jj*16 + d  ->  n' = jj*64 + gate*16 + d
// so each recurrence block's per-(b,t) slice is 64 contiguous values.
__global__ __launch_bounds__(256, 2) void kgemm(const ushort_t* __restrict__ A,
                                                const ushort_t* __restrict__ Bm,
                                                const float* __restrict__ bias,
                                                ushort_t* __restrict__ C) {
    __shared__ __align__(16) ushort_t LA[4096];   // [128 rows][32 k] swizzled
    __shared__ __align__(16) ushort_t LB[4096];
    const int tid = threadIdx.x;
    const int lane = tid & 63, w = tid >> 6;
    const int quad = lane >> 4, l16 = lane & 15;
    const int bn = blockIdx.x, bm = blockIdx.y;
    const int wr = w >> 1, wc = w & 1;

    f32x4 acc[4][4] = {};

    for (int kt = 0; kt < 16; ++kt) {
#pragma unroll
        for (int r = 0; r < 2; ++r) {
            int o = r * 256 + tid;           // 16B unit index
            int m = o >> 2, slot = o & 3;
            int kc = slot ^ ((m >> 1) & 3);  // stored slot = kc ^ s(m)
            const ushort_t* ga = A  + (size_t)(bm * 128 + m) * I_ + kt * 32 + kc * 8;
            const ushort_t* gb = Bm + (size_t)(bn * 128 + m) * I_ + kt * 32 + kc * 8;
            __builtin_amdgcn_global_load_lds(
                (const __attribute__((address_space(1))) void*)ga,
                (__attribute__((address_space(3))) void*)(&LA[r * 2048 + w * 512]), 16, 0, 0);
            __builtin_amdgcn_global_load_lds(
                (const __attribute__((address_space(1))) void*)gb,
                (__attribute__((address_space(3))) void*)(&LB[r * 2048 + w * 512]), 16, 0, 0);
        }
        __syncthreads();

        short8 av[4], bv[4];
#pragma unroll
        for (int mt = 0; mt < 4; ++mt) {
            int mm = wr * 64 + mt * 16 + l16;
            av[mt] = *(const short8*)&LA[mm * 32 + ((quad ^ ((mm >> 1) & 3)) << 3)];
            int nn = wc * 64 + mt * 16 + l16;
            bv[mt] = *(const short8*)&LB[nn * 32 + ((quad ^ ((nn >> 1) & 3)) << 3)];
        }
#pragma unroll
        for (int mt = 0; mt < 4; ++mt)
#pragma unroll
            for (int nt = 0; nt < 4; ++nt)
                acc[mt][nt] = __builtin_amdgcn_mfma_f32_16x16x32_bf16(av[mt], bv[nt], acc[mt][nt], 0, 0, 0);
        __syncthreads();
    }

#pragma unroll
    for (int nt = 0; nt < 4; ++nt) {
        int n = bn * 128 + wc * 64 + nt * 16 + l16;      // logical gate-space column
        int gate = n >> 9, jj = (n >> 4) & 31, d = n & 15;
        int np = jj * 64 + gate * 16 + d;                // swizzled storage column
        float bvl = bias[n];
#pragma unroll
        for (int mt = 0; mt < 4; ++mt) {
#pragma unroll
            for (int rg = 0; rg < 4; ++rg) {
                int m = bm * 128 + wr * 64 + mt * 16 + quad * 4 + rg;
                C[(size_t)m * G_ + np] = f2bf(acc[mt][nt][rg] + bvl);
            }
        }
    }
}

// ---------- recurrence ----------
// 256 blocks, 1/CU, 8 XCD-pure groups x 32 via the HW roster (hwreg(HW_REG_XCC_ID) +
// lexicographic rank + global purity AND-vote — proven rounds 8/10/11/12).
//
// ROUND-12 LESSON (vmcnt FIFO discipline): __hip_atomic_load emits s_waitcnt vmcnt(0),
// and vmcnt retires IN ISSUE ORDER — every poll sweep first drains ALL older outstanding
// VMEM. The gx prefetch (4 HBM loads, ~600-900cy) was issued at the top of each step,
// right before the poll: the first sweep of EVERY step stalled on gx data not needed
// until the cell phase ~2000cy later, and gx HBM tail latency fed the max-of-32 skew.
// THIS ROUND: gx is software-pipelined ONE STEP AHEAD — preloaded before the loop, and
// each step issues n+1's loads AFTER the exchange phase's last vmcnt-bearing atomic
// (post-unpack), sandwiched in sched_barrier(0) so the compiler cannot hoist them back
// above the poll (guide rule #18). By the next poll they are a full step old = retired.
//
// Exchange (proven round 11/12): data unit = 8B of 4 bf16 dims (tag-free), plain
// write-back stores into the shared XCD L2; producer order h-stores -> vmcnt(0)
// (local-L2 ack) -> per-consumer private done copies (32 x 512B apart). Consumer polls
// only its own done slot (1 atomic load/lane/sweep), then one-shot atomic-loads its 4
// data units (L1-bypass — round-9 staleness lesson). Overwrite safety = 2-step lag
// invariant (done>=n implies old-parity reads complete, by program order through MFMA).
// Impure placement: round-2-proven tagged AGENT path verbatim. All spins capped: any
// failure = bounded-time wrong answer, no hang. Replay-safe: done monotone + '>='.
__global__ __launch_bounds__(256, 1) void krec(const ushort_t* __restrict__ gx,
                                               const ushort_t* __restrict__ whb,
                                               unsigned long long* __restrict__ hgf,
                                               unsigned long long* __restrict__ hga,
                                               unsigned long long* __restrict__ dn,
                                               uint32_t* __restrict__ xtab,
                                               float* __restrict__ out) {
    __shared__ __align__(16) ushort_t hl[16 * 520];   // h tile, padded stride (rows 8-15 stay 0)
    __shared__ float gates[4][16][16];                // [gate][chain][dim]
    __shared__ uint32_t sx[256];
    __shared__ int s_grp, s_j, s_pure;
    const int tid = threadIdx.x;
    const int lane = tid & 63, w = tid >> 6;
    const int quad = lane >> 4, l16 = lane & 15;
    const int bk = blockIdx.x;

    // zero hl once: MFMA A-frags read all 16 rows; rows 8-15 are never written in the loop.
    for (int t = tid; t < (16 * 520) / 2; t += 256) ((uint32_t*)hl)[t] = 0;

    // ---- roster phase 1: discover XCD, publish, gather, rank ----
    uint32_t xcd;
    asm("s_getreg_b32 %0, hwreg(HW_REG_XCC_ID)" : "=s"(xcd));
    xcd &= 7u;
    if (tid == 0)
        __hip_atomic_store(&xtab[bk], 0x100u | xcd, __ATOMIC_RELAXED, __HIP_MEMORY_SCOPE_AGENT);
    {
        uint32_t e = 0;
        for (int spin = 0; spin < (1 << 16); ++spin) {   // ~20ms cap
            e = __hip_atomic_load(&xtab[tid], __ATOMIC_RELAXED, __HIP_MEMORY_SCOPE_AGENT);
            if (e & 0x100u) break;
            __builtin_amdgcn_s_sleep(8);
        }
        sx[tid] = e;
    }
    __syncthreads();
    if (tid == 0) {
        int cnt[8] = {0,0,0,0,0,0,0,0};
        int allvalid = 1;
        for (int i = 0; i < 256; ++i) {
            if (!(sx[i] & 0x100u)) allvalid = 0;
            cnt[sx[i] & 7u]++;
        }
        int balanced = allvalid;
        for (int x = 0; x < 8; ++x) if (cnt[x] != 32) balanced = 0;
        int pre[9]; pre[0] = 0;
        for (int x = 0; x < 8; ++x) pre[x + 1] = pre[x] + cnt[x];
        int rank = pre[xcd];
        for (int i = 0; i < bk; ++i) if ((sx[i] & 7u) == xcd) rank++;
        s_grp = rank >> 5; s_j = rank & 31;
        __hip_atomic_store(&xtab[256 + bk], 0x200u | (uint32_t)balanced,
                           __ATOMIC_RELAXED, __HIP_MEMORY_SCOPE_AGENT);
    }
    __syncthreads();
    // ---- roster phase 2: gather purity votes, global AND ----
    {
        uint32_t v = 0;
        for (int spin = 0; spin < (1 << 16); ++spin) {
            v = __hip_atomic_load(&xtab[256 + tid], __ATOMIC_RELAXED, __HIP_MEMORY_SCOPE_AGENT);
            if (v & 0x200u) break;
            __builtin_amdgcn_s_sleep(8);
        }
        sx[tid] = (v & 0x200u) ? (v & 1u) : 0u;   // timeout counts as impure vote
    }
    __syncthreads();
    if (tid == 0) {
        int p = 1;
        for (int i = 0; i < 256; ++i) p &= (int)sx[i];
        s_pure = p;
    }
    __syncthreads();
    const int grp = s_grp, j = s_j;
    const bool pure = (s_pure != 0);

    // Wh B-frags for this wave's gate section, cols j*16..+16 (rows of Wh = gate outputs)
    short8 bw[16];
    {
        const ushort_t* wp = whb + (size_t)(w * H_ + j * 16 + l16) * H_ + quad * 8;
#pragma unroll
        for (int kc = 0; kc < 16; ++kc) bw[kc] = *(const short8*)(wp + kc * 32);
    }

    const int r = tid >> 4, d = tid & 15;     // consumer role: r in 0..15, d in 0..15
    const int rr = r & 7, half = r >> 3;      // chain, coverage-half
    const bool cell = (tid < 128);            // cell-update threads: chain r (0..7), dim d
    const int b = grp * 4 + (r & 3), dir = (r >> 2) & 1;
    const int cwave = tid >> 6;               // cell waves are 0 and 1
    float c = 0.0f;                           // cell state in register

    unsigned long long* hgrpF = hgf + (size_t)grp * 2048;   // fast: 2 par x 1024 tag-free units
    unsigned long long* hgrpA = hga + (size_t)grp * 4096;   // agent path: 2 par x 2048 tagged
    unsigned long long* dgrp  = dn  + (size_t)grp * 2048;   // 32 consumer copies x 64 slots

    // pure consumer: 4 data units at rr*128 + half*64 + d*4 + {0..3} (32B, one line),
    // produced by block jp = half*16+d, cell wave rr>>2. Private done slot:
    const int myslot = (half * 16 + d) * 2 + (rr >> 2);
    const unsigned long long* mydone = dgrp + (size_t)j * 64 + myslot;
    const int fbase = rr * 128 + half * 64 + d * 4;
    // impure consumer: 8 tagged units at rr*256 + half*128 + d*4 (+64)
    const int abase = rr * 256 + half * 128 + d * 4;

    // ---- gx software pipeline: preload step 0 (HBM latency absorbed once) ----
    ushort_t g0 = 0, g1 = 0, g2 = 0, g3 = 0;
    if (cell) {
        int te = dir ? 511 : 0;
        const ushort_t* gp = gx + (size_t)(b * T_ + te) * G_ + j * 64 + d;
        g0 = gp[0]; g1 = gp[16]; g2 = gp[32]; g3 = gp[48];
    }

    for (int n = 0; n < 512; ++n) {
        const uint32_t un = (uint32_t)n;

        if (pure) {
            // ---- private done poll: 1 atomic load/lane/sweep, own 8-line region.
            //      vmcnt queue is clean: no HBM loads outstanding (gx pipelined). ----
            for (int spin = 0; spin < 4096; ++spin) {
                unsigned long long v = __hip_atomic_load(mydone, __ATOMIC_RELAXED,
                                                         __HIP_MEMORY_SCOPE_AGENT);
                if (__all((uint32_t)v >= un)) break;
            }
            // ---- one-shot data load: 4 atomic 8B loads (L1-bypass), one 64B line ----
            const unsigned long long* f0 = hgrpF + (size_t)(n & 1) * 1024 + fbase;
            unsigned long long t0 = __hip_atomic_load(f0 + 0, __ATOMIC_RELAXED, __HIP_MEMORY_SCOPE_AGENT);
            unsigned long long t1 = __hip_atomic_load(f0 + 1, __ATOMIC_RELAXED, __HIP_MEMORY_SCOPE_AGENT);
            unsigned long long t2 = __hip_atomic_load(f0 + 2, __ATOMIC_RELAXED, __HIP_MEMORY_SCOPE_AGENT);
            unsigned long long t3 = __hip_atomic_load(f0 + 3, __ATOMIC_RELAXED, __HIP_MEMORY_SCOPE_AGENT);
            // ---- unpack 16 dims to LDS: 2x ds_write_b128 ----
            uint4 p0, p1;
            p0.x = (uint32_t)t0; p0.y = (uint32_t)(t0 >> 32);
            p0.z = (uint32_t)t1; p0.w = (uint32_t)(t1 >> 32);
            p1.x = (uint32_t)t2; p1.y = (uint32_t)(t2 >> 32);
            p1.z = (uint32_t)t3; p1.w = (uint32_t)(t3 >> 32);
            int hb = rr * 520 + half * 256 + d * 16;
            *(uint4*)&hl[hb] = p0;
            *(uint4*)&hl[hb + 8] = p1;
        } else {
            // ---- AGENT path (round-2/5-proven), tagged units, sleep-throttled ----
            const unsigned long long* a0 = hgrpA + (size_t)(n & 1) * 2048 + abase;
            unsigned long long tv[8];
            for (int spin = 0; spin < 600; ++spin) {
#pragma unroll
                for (int i = 0; i < 8; ++i)
                    tv[i] = __hip_atomic_load(a0 + (i >> 2) * 64 + (i & 3),
                                              __ATOMIC_RELAXED, __HIP_MEMORY_SCOPE_AGENT);
                bool ok = true;
#pragma unroll
                for (int i = 0; i < 8; ++i)
                    ok &= ((uint32_t)(tv[i] >> 32) >= un);
                if (ok) break;
                __builtin_amdgcn_s_sleep(4);
            }
#pragma unroll
            for (int cc = 0; cc < 2; ++cc) {
                uint4 pk;
                pk.x = (uint32_t)tv[cc * 4 + 0];
                pk.y = (uint32_t)tv[cc * 4 + 1];
                pk.z = (uint32_t)tv[cc * 4 + 2];
                pk.w = (uint32_t)tv[cc * 4 + 3];
                *(uint4*)&hl[rr * 520 + half * 256 + cc * 128 + d * 8] = pk;
            }
        }

        // ---- issue gx prefetch for step n+1 HERE: after the exchange phase's last
        //      vmcnt-bearing atomic, ~1 full step before the next poll. sched_barrier
        //      fences pin the issue point against compiler motion (rule #18). ----
        ushort_t p0g = 0, p1g = 0, p2g = 0, p3g = 0;
        __builtin_amdgcn_sched_barrier(0);
        if (cell && n < 511) {
            int te = dir ? (510 - n) : (n + 1);
            const ushort_t* gp = gx + (size_t)(b * T_ + te) * G_ + j * 64 + d;
            p0g = gp[0]; p1g = gp[16]; p2g = gp[32]; p3g = gp[48];
        }
        __builtin_amdgcn_sched_barrier(0);
        __syncthreads();

        // ---- gates = h @ Wh_section^T (two independent MFMA chains) ----
        f32x4 acc0 = {}, acc1 = {};
#pragma unroll
        for (int kc = 0; kc < 16; kc += 2) {
            short8 av0 = *(const short8*)&hl[l16 * 520 + kc * 32 + quad * 8];
            acc0 = __builtin_amdgcn_mfma_f32_16x16x32_bf16(av0, bw[kc], acc0, 0, 0, 0);
            short8 av1 = *(const short8*)&hl[l16 * 520 + (kc + 1) * 32 + quad * 8];
            acc1 = __builtin_amdgcn_mfma_f32_16x16x32_bf16(av1, bw[kc + 1], acc1, 0, 0, 0);
        }
        f32x4 acc = acc0 + acc1;
#pragma unroll
        for (int rg = 0; rg < 4; ++rg) gates[w][quad * 4 + rg][l16] = acc[rg];
        __syncthreads();

        // ---- cell update: thread -> (chain r, dim d), chains 0..7 only ----
        if (cell) {
            float gi = gates[0][r][d] + bf2f(g0);
            float gf = gates[1][r][d] + bf2f(g1);
            float gg = gates[2][r][d] + bf2f(g2);
            float go = gates[3][r][d] + bf2f(g3);
            float it = sigm(gi), ft = sigm(gf), gt = tanhx(gg), ot = sigm(go);
            c = c * ft + it * gt;
            float h = ot * tanhx(c);

            int hv = (int)f2bf(h);
            if (pure) {
                // ---- tag-free publish: 4 dims/unit, ack, then 32 private done copies ----
                int v1 = __shfl(hv, lane + 1);
                int v2 = __shfl(hv, lane + 2);
                int v3 = __shfl(hv, lane + 3);
                if (!(d & 3)) {
                    uint2 uv;
                    uv.x = ((uint32_t)hv & 0xFFFFu) | ((uint32_t)v1 << 16);
                    uv.y = ((uint32_t)v2 & 0xFFFFu) | ((uint32_t)v3 << 16);
                    unsigned long long* fp = hgrpF + (size_t)((n + 1) & 1) * 1024
                                           + (size_t)r * 128 + j * 4 + (d >> 2);
                    asm volatile("global_store_dwordx2 %0, %1, off"
                                 :: "v"((void*)fp), "v"(uv) : "memory");
                }
                asm volatile("s_waitcnt vmcnt(0)");   // local-L2 acks (+ rare gx tail)
                if (lane < 32) {
                    uint2 dv; dv.x = (uint32_t)(n + 1); dv.y = 0;
                    unsigned long long* dp = dgrp + (size_t)lane * 64 + (size_t)j * 2 + cwave;
                    asm volatile("global_store_dwordx2 %0, %1, off"
                                 :: "v"((void*)dp), "v"(dv) : "memory");
                }
            } else {
                // ---- tagged agent publish (fabric) ----
                int vo = __shfl(hv, lane ^ 1);
                if (!(d & 1)) {
                    uint32_t payv = (((uint32_t)vo & 0xFFFFu) << 16) | ((uint32_t)hv & 0xFFFFu);
                    unsigned long long unit =
                        ((unsigned long long)(uint32_t)(n + 1) << 32) | payv;
                    size_t u = (size_t)((n + 1) & 1) * 2048 + (size_t)r * 256 + j * 8 + (d >> 1);
                    __hip_atomic_store(hgrpA + u, unit,
                                       __ATOMIC_RELAXED, __HIP_MEMORY_SCOPE_AGENT);
                }
            }
            out[(size_t)b * (T_ * 2 * H_) + (size_t)n * (2 * H_) + dir * H_ + j * 16 + d] = h;
        }

        // rotate gx pipeline registers
        g0 = p0g; g1 = p1g; g2 = p2g; g3 = p3g;
    }
}

// ---------- workspace layout (bytes) ----------
// HGF/HGA/DONE/XTAB alias XB: xb is dead after kgemm; memset issued after kgemm in-stream.
#define GX_OFF    ((size_t)0)                    // 16384*2048*2 = 67108864
#define XB_OFF    ((size_t)67108864)             // 16384*512*2 = 16777216
#define HGF_OFF   XB_OFF                         // 8 grp * 2 par * 1024 units * 8B = 131072
#define HGA_OFF   (XB_OFF + 131072)              // 8 grp * 2 par * 2048 units * 8B = 262144
#define DONE_OFF  (XB_OFF + 393216)              // 8 grp * 32 copies * 64 slots * 8B = 131072
#define XTAB_OFF  (XB_OFF + 524288)              // 512 * 4 = 2048
#define HG_BYTES  ((size_t)(524288 + 2048))
#define WXB_OFF   ((size_t)83886080)             // 2048*512*2  = 2097152
#define WHB_OFF   ((size_t)85983232)             // 2048*512*2  = 2097152
#define BIAS_OFF  ((size_t)88080384)             // 2048*4      = 8192
#define WS_NEED   ((size_t)88088576)

extern "C" void kernel_launch(void* const* d_in, const int* in_sizes, int n_in,
                              void* d_out, int out_size, void* d_ws, size_t ws_size,
                              hipStream_t stream) {
    if (ws_size < WS_NEED) return;

    const float* x  = (const float*)d_in[0];
    const float* Wx = (const float*)d_in[1];
    const float* bx = (const float*)d_in[2];
    const float* Wh = (const float*)d_in[3];
    const float* bh = (const float*)d_in[4];
    float* out = (float*)d_out;
    char* ws = (char*)d_ws;

    ushort_t* gx   = (ushort_t*)(ws + GX_OFF);
    ushort_t* xb   = (ushort_t*)(ws + XB_OFF);
    ushort_t* wxb  = (ushort_t*)(ws + WXB_OFF);
    ushort_t* whb  = (ushort_t*)(ws + WHB_OFF);
    float*    bias = (float*)(ws + BIAS_OFF);
    unsigned long long* hgf = (unsigned long long*)(ws + HGF_OFF);
    unsigned long long* hga = (unsigned long long*)(ws + HGA_OFF);
    unsigned long long* dn  = (unsigned long long*)(ws + DONE_OFF);
    uint32_t* xtab = (uint32_t*)(ws + XTAB_OFF);

    // casts
    kcast<<<dim3((B_ * T_ * I_ / 4 + 255) / 256), 256, 0, stream>>>(x, xb, B_ * T_ * I_ / 4);
    kcast<<<dim3((G_ * I_ / 4 + 255) / 256), 256, 0, stream>>>(Wx, wxb, G_ * I_ / 4);
    kcast<<<dim3((G_ * H_ / 4 + 255) / 256), 256, 0, stream>>>(Wh, whb, G_ * H_ / 4);
    kbias<<<dim3(G_ / 256), 256, 0, stream>>>(bx, bh, bias);

    // input projection GEMM: grid (N/128, M/128) = (16, 128)
    kgemm<<<dim3(G_ / 128, (B_ * T_) / 128), 256, 0, stream>>>(xb, wxb, bias, gx);

    // zero fast/agent h buffers + private done copies + roster/vote table.
    // memset-0 == valid step-0 state (h0 = 0, done = 0 >= 0, tags = 0).
    // Must run after kgemm: they alias the then-dead xb region.
    hipMemsetAsync(ws + HGF_OFF, 0, HG_BYTES, stream);

    // recurrence: 256 persistent blocks (8 XCD-pure groups x 32), one per CU
    krec<<<dim3(256), 256, 0, stream>>>(gx, whb, hgf, hga, dn, xtab, out);
}